// Round 4
// baseline (432.405 us; speedup 1.0000x reference)
//
#include <hip/hip_runtime.h>

#define N_MET 250000
#define N_RXN 500000
#define E_SUB 2000000
#define E_ALL 4000000
#define DT 0.01f

#define RXN_PER_BLK 256
#define THREADS 256
#define EDGE_CAP 1536   // k_edge_mv LDS staging cap; global fallback below
#define TPAD 72         // padded K for per-wave T tiles (64 + 8)

#define MV_RPB 64       // k_rscale reactions per block (4 waves x 16)

// ---- binning geometry ----
#define BINSZ 512
#define MSHIFT 9                                            // met bin shift (log2 BINSZ)
#define NBINS ((N_MET + BINSZ - 1) / BINSZ)                 // 489
#define PART_EPB 4096
#define PTHREADS 512                                        // part_sorted block size
#define KPB (PART_EPB / PTHREADS)                           // 8 keys/thread
#define PART_NBLK ((E_ALL + PART_EPB - 1) / PART_EPB)       // 977
#define SPART_NBLK ((E_SUB + PART_EPB - 1) / PART_EPB)      // 489
#define RBINSZ 1024
#define RSHIFT 10                                           // rxn bin shift
#define RNBINS ((N_RXN + RBINSZ - 1) / RBINSZ)              // 489
#define RPART_NBLK ((E_SUB + PART_EPB - 1) / PART_EPB)      // 489

typedef int v4i __attribute__((ext_vector_type(4)));
typedef float v4f __attribute__((ext_vector_type(4)));
typedef short bf16x8 __attribute__((ext_vector_type(8)));
typedef float f32x4 __attribute__((ext_vector_type(4)));

// fast exp2 / rcp mapping straight to v_exp_f32 / v_rcp_f32
#if __has_builtin(__builtin_amdgcn_exp2f)
#define EXP2F(x) __builtin_amdgcn_exp2f(x)
#else
#define EXP2F(x) exp2f(x)
#endif
#if __has_builtin(__builtin_amdgcn_rcpf)
#define RCPF(x) __builtin_amdgcn_rcpf(x)
#else
#define RCPF(x) __fdividef(1.0f, (x))
#endif

static __device__ __forceinline__ float fast_tanh(float x) {
  float e = __expf(x + x);
  return 1.0f - __fdividef(2.0f, e + 1.0f);
}

static __device__ __forceinline__ int bcast_i(int v, int lane) {
  return __builtin_amdgcn_readlane(v, lane);
}

static __device__ __forceinline__ unsigned short bf16_rn(float f) {
  unsigned u = __float_as_uint(f);
  unsigned r = u + 0x7FFFu + ((u >> 16) & 1u);
  return (unsigned short)(r >> 16);
}

// ==== fused: bin-counts for all 3 partitions + conc extraction + W23 precompute ====
__global__ __launch_bounds__(256) void k_bc3(
    const int* __restrict__ rxn_sub, const int* __restrict__ met_sub,
    const int* __restrict__ met_all,
    const float* __restrict__ x, float* __restrict__ conc,
    const float* __restrict__ W2, const float* __restrict__ W3,
    const float* __restrict__ b2,
    uint4* __restrict__ wfh, uint4* __restrict__ wfl, float* __restrict__ b2w3,
    int* __restrict__ rblk_cnt, int* __restrict__ sblk_cnt, int* __restrict__ blk_cnt) {
  __shared__ int cnt[RNBINS > NBINS ? RNBINS : NBINS];   // 489
  int b = blockIdx.x, t = threadIdx.x;
  const int* keys; int nkeys, nblk, nb, bl, shift; int* out;
  if (b < RPART_NBLK) {
    keys = rxn_sub; nkeys = E_SUB; nblk = RPART_NBLK; nb = RNBINS; out = rblk_cnt;
    bl = b; shift = RSHIFT;
    if (b < 2) {
      // ---- k_pre: MFMA B-fragments of W23 = W2@W3 (bf16 hi/lo) and b2@W3 ----
      int tid = b * 256 + t;
      if (tid < 512) {
        int lane = tid & 63, jt = (tid >> 6) & 3, ks = tid >> 8;
        int jj = jt * 16 + (lane & 15);
        unsigned short h[8], l[8];
        #pragma unroll
        for (int q = 0; q < 8; ++q) {
          int kk = ks * 32 + (lane >> 4) * 8 + q;
          float w = 0.f;
          #pragma unroll
          for (int m = 0; m < 32; ++m) w = fmaf(W2[kk * 32 + m], W3[m * 64 + jj], w);
          h[q] = bf16_rn(w);
          float hf = __uint_as_float(((unsigned)h[q]) << 16);
          l[q] = bf16_rn(w - hf);
        }
        uint4 H, L;
        H.x = (unsigned)h[0] | ((unsigned)h[1] << 16);
        H.y = (unsigned)h[2] | ((unsigned)h[3] << 16);
        H.z = (unsigned)h[4] | ((unsigned)h[5] << 16);
        H.w = (unsigned)h[6] | ((unsigned)h[7] << 16);
        L.x = (unsigned)l[0] | ((unsigned)l[1] << 16);
        L.y = (unsigned)l[2] | ((unsigned)l[3] << 16);
        L.z = (unsigned)l[4] | ((unsigned)l[5] << 16);
        L.w = (unsigned)l[6] | ((unsigned)l[7] << 16);
        int idx = (ks * 4 + jt) * 64 + lane;
        wfh[idx] = H; wfl[idx] = L;
      }
      if (tid < 64) {
        float s = 0.f;
        #pragma unroll
        for (int m = 0; m < 32; ++m) s = fmaf(b2[m], W3[m * 64 + tid], s);
        b2w3[tid] = s;
      }
    }
  } else if (b < RPART_NBLK + SPART_NBLK) {
    keys = met_sub; nkeys = E_SUB; nblk = SPART_NBLK; nb = NBINS; out = sblk_cnt;
    bl = b - RPART_NBLK; shift = MSHIFT;
  } else {
    keys = met_all; nkeys = E_ALL; nblk = PART_NBLK; nb = NBINS; out = blk_cnt;
    bl = b - RPART_NBLK - SPART_NBLK; shift = MSHIFT;
    int m = bl * 256 + t;
    if (m < N_MET) conc[m] = __builtin_nontemporal_load(x + m * 8 + 3);
  }
  for (int i = t; i < nb; i += 256) cnt[i] = 0;
  __syncthreads();
  int base = bl * PART_EPB;
  #pragma unroll
  for (int i = 0; i < PART_EPB / 256; ++i) {
    int e = base + i * 256 + t;
    if (e < nkeys) atomicAdd(&cnt[__builtin_nontemporal_load(keys + e) >> shift], 1);
  }
  __syncthreads();
  for (int i = t; i < nb; i += 256) out[i * nblk + bl] = cnt[i];
}

// ==== fused scans ====
static __device__ __forceinline__ void scan1_body(int* ss,
    const int* __restrict__ blk_cnt, int* __restrict__ blk_pref,
    int* __restrict__ bin_tot, int nblk, int j) {
  int t = threadIdx.x;
  int carry = 0;
  for (int c = 0; c < nblk; c += 256) {
    int idx = c + t;
    int v = (idx < nblk) ? blk_cnt[j * nblk + idx] : 0;
    ss[t] = v; __syncthreads();
    for (int d = 1; d < 256; d <<= 1) {
      int a = (t >= d) ? ss[t - d] : 0;
      __syncthreads();
      ss[t] += a;
      __syncthreads();
    }
    if (idx < nblk) blk_pref[j * nblk + idx] = carry + ss[t] - v;
    carry += ss[255];
    __syncthreads();
  }
  if (t == 0) bin_tot[j] = carry;
}

__global__ __launch_bounds__(256) void k_scan1all(
    const int* __restrict__ rblk_cnt, int* __restrict__ rblk_pref, int* __restrict__ rbin_tot,
    const int* __restrict__ sblk_cnt, int* __restrict__ sblk_pref, int* __restrict__ sbin_tot,
    const int* __restrict__ blk_cnt, int* __restrict__ blk_pref, int* __restrict__ bin_tot) {
  __shared__ int ss[256];
  int b = blockIdx.x;
  if (b < RNBINS)
    scan1_body(ss, rblk_cnt, rblk_pref, rbin_tot, RPART_NBLK, b);
  else if (b < RNBINS + NBINS)
    scan1_body(ss, sblk_cnt, sblk_pref, sbin_tot, SPART_NBLK, b - RNBINS);
  else
    scan1_body(ss, blk_cnt, blk_pref, bin_tot, PART_NBLK, b - RNBINS - NBINS);
}

__global__ __launch_bounds__(512) void k_scan2all(
    const int* __restrict__ rbin_tot, int* __restrict__ rbin_start,
    const int* __restrict__ sbin_tot, int* __restrict__ sbin_start,
    const int* __restrict__ bin_tot, int* __restrict__ bin_start) {
  __shared__ int ss[512];
  const int* tot; int* st; int n;
  if (blockIdx.x == 0)      { tot = rbin_tot; st = rbin_start; n = RNBINS; }
  else if (blockIdx.x == 1) { tot = sbin_tot; st = sbin_start; n = NBINS; }
  else                      { tot = bin_tot;  st = bin_start;  n = NBINS; }
  int t = threadIdx.x;
  int v = (t < n) ? tot[t] : 0;
  ss[t] = v; __syncthreads();
  for (int d = 1; d < 512; d <<= 1) {
    int a = (t >= d) ? ss[t - d] : 0;
    __syncthreads();
    ss[t] += a;
    __syncthreads();
  }
  if (t < n) st[t] = ss[t] - v;
}

// ==== block-locally-sorted partition: records leave as contiguous bursts ====
// 512 threads, 8 keys/thread. PACK=true: rec.x carries the full key (bin = rec.x>>SHIFT),
// so the binb[] side-array is eliminated (saves 8 KB LDS -> 4 blocks/CU).
template <int NB, int SHIFT, bool PACK, typename MakeRec>
static __device__ __forceinline__ void part_sorted(
    const int* __restrict__ keys, int nkeys, int nblk,
    const int* __restrict__ blk_pref, const int* __restrict__ bin_start,
    int2* __restrict__ out, MakeRec make) {
  __shared__ int2 ordered[PART_EPB];                        // 32 KB
  __shared__ unsigned short binb[PACK ? 1 : PART_EPB];      // 8 KB only if !PACK
  __shared__ int cnt[NB];
  __shared__ int gofs[NB];
  __shared__ int ss[PTHREADS];
  int b = blockIdx.x, t = threadIdx.x;
  for (int i = t; i < NB; i += PTHREADS) cnt[i] = 0;
  __syncthreads();
  int base = b * PART_EPB;
  int kbuf[KPB];
  #pragma unroll
  for (int i = 0; i < KPB; ++i) {
    int e = base + i * PTHREADS + t;
    kbuf[i] = (e < nkeys) ? __builtin_nontemporal_load(keys + e) : -1;
    if (kbuf[i] >= 0) atomicAdd(&cnt[kbuf[i] >> SHIFT], 1);
  }
  __syncthreads();
  // single-chunk scan (NB <= PTHREADS); cnt becomes cursor, gofs = global - lstart
  int v = (t < NB) ? cnt[t] : 0;
  ss[t] = v; __syncthreads();
  for (int d = 1; d < PTHREADS; d <<= 1) {
    int a = (t >= d) ? ss[t - d] : 0;
    __syncthreads();
    ss[t] += a;
    __syncthreads();
  }
  int nloc = ss[PTHREADS - 1];
  if (t < NB) {
    int ls = ss[t] - v;
    cnt[t] = ls;  // becomes cursor
    gofs[t] = bin_start[t] + blk_pref[t * nblk + b] - ls;
  }
  __syncthreads();
  // pass B: place records bin-ordered in LDS
  #pragma unroll
  for (int i = 0; i < KPB; ++i) {
    int k = kbuf[i];
    if (k >= 0) {
      int e = base + i * PTHREADS + t;
      int bin = k >> SHIFT;
      int2 rec = make(e, k);
      int pos = atomicAdd(&cnt[bin], 1);  // LDS atomic
      ordered[pos] = rec;
      if (!PACK) binb[pos] = (unsigned short)bin;
    }
  }
  __syncthreads();
  // pass C: ordered, coalesced burst copy
  for (int i = t; i < nloc; i += PTHREADS) {
    int2 rec = ordered[i];
    int bin = PACK ? (int)(((unsigned)rec.x) >> SHIFT) : (int)binb[i];
    out[gofs[bin] + i] = rec;
  }
}

// CSR partition: packed {rloc:10|m:18, sto} by rxn-bin (no spare bits -> binb path)
__global__ __launch_bounds__(PTHREADS) void k_rpart(
    const int* __restrict__ rxn_sub, const int* __restrict__ met_sub,
    const float* __restrict__ sto_sub,
    const int* __restrict__ blk_pref, const int* __restrict__ bin_start,
    int2* __restrict__ bins_rxn) {
  part_sorted<RNBINS, RSHIFT, false>(rxn_sub, E_SUB, RPART_NBLK, blk_pref, bin_start,
                                     bins_rxn,
    [=] __device__ (int e, int k) {
      int m = __builtin_nontemporal_load(met_sub + e);
      float st = __builtin_nontemporal_load(sto_sub + e);
      int2 rec; rec.x = ((k & (RBINSZ - 1)) << 18) | m; rec.y = __float_as_int(st);
      return rec;
    });
}

// consumption partition: {k(full met idx), sto*v_pre[r]*DT} by met-bin
__global__ __launch_bounds__(PTHREADS) void k_part_sub(
    const int* __restrict__ met_sub, const int* __restrict__ rxn_sub,
    const float* __restrict__ sto_sub, const float* __restrict__ v_pre,
    const int* __restrict__ blk_pref, const int* __restrict__ bin_start,
    int2* __restrict__ bins_sub) {
  part_sorted<NBINS, MSHIFT, true>(met_sub, E_SUB, SPART_NBLK, blk_pref, bin_start,
                                   bins_sub,
    [=] __device__ (int e, int k) {
      int r = __builtin_nontemporal_load(rxn_sub + e);
      float st = __builtin_nontemporal_load(sto_sub + e);
      float val = st * v_pre[r] * DT;
      int2 rec; rec.x = k; rec.y = __float_as_int(val);
      return rec;
    });
}

// dxdt partition: {k(full met idx), sto*vfin[r]} by met-bin
__global__ __launch_bounds__(PTHREADS) void k_part(
    const int* __restrict__ met_all, const int* __restrict__ rxn_all,
    const float* __restrict__ sto_all, const float* __restrict__ vfin,
    const int* __restrict__ blk_pref, const int* __restrict__ bin_start,
    int2* __restrict__ bins) {
  part_sorted<NBINS, MSHIFT, true>(met_all, E_ALL, PART_NBLK, blk_pref, bin_start, bins,
    [=] __device__ (int e, int k) {
      int r = __builtin_nontemporal_load(rxn_all + e);
      float st = __builtin_nontemporal_load(sto_all + e);
      float val = st * vfin[r];
      int2 rec; rec.x = k; rec.y = __float_as_int(val);
      return rec;
    });
}

// ==== CSR per-bin local sort -> edges8 CSR order + off[] ====
// 512 threads, no LDS staging (bins_rxn slice is L2-resident; re-read is ~free,
// dropping the 48 KB stage buffer takes occupancy 8 -> ~16 waves/CU).
__global__ __launch_bounds__(512) void k_rbin(
    const int2* __restrict__ bins_rxn, const int* __restrict__ rbin_start,
    const int* __restrict__ rbin_tot, int2* __restrict__ edges8, int* __restrict__ off) {
  __shared__ int lcnt[RBINSZ];
  __shared__ int lcur[RBINSZ];
  __shared__ int ss[512];
  int j = blockIdx.x, t = threadIdx.x;
  int base = rbin_start[j], n = rbin_tot[j];
  for (int i = t; i < RBINSZ; i += 512) lcnt[i] = 0;
  __syncthreads();
  for (int i = t; i < n; i += 512) {
    int2 rec = bins_rxn[base + i];
    atomicAdd(&lcnt[((unsigned)rec.x) >> 18], 1);
  }
  __syncthreads();
  int s0 = lcnt[2 * t], s1 = lcnt[2 * t + 1];
  int tsum = s0 + s1;
  ss[t] = tsum; __syncthreads();
  for (int d = 1; d < 512; d <<= 1) {
    int a = (t >= d) ? ss[t - d] : 0;
    __syncthreads();
    ss[t] += a;
    __syncthreads();
  }
  int run = ss[t] - tsum;
  lcur[2 * t] = run;
  lcur[2 * t + 1] = run + s0;
  __syncthreads();
  int R0 = j * RBINSZ;
  for (int rl = t; rl < RBINSZ; rl += 512) {
    int r = R0 + rl;
    if (r < N_RXN) off[r] = base + lcur[rl];
  }
  if (j == 0 && t == 0) off[N_RXN] = E_SUB;
  __syncthreads();
  for (int i = t; i < n; i += 512) {
    int2 rec = bins_rxn[base + i];
    int pos = atomicAdd(&lcur[((unsigned)rec.x) >> 18], 1);
    int2 o; o.x = rec.x & 0x3FFFF; o.y = rec.y;
    edges8[base + pos] = o;
  }
}

// ---- k_edge_mv: fused edge tanh-sum + MFMA (T never leaves the CU) ----
// Math: sum_e tanh(x_e) = n - 2 * sum_e 1/(1 + exp2(C2*x_e)), C2 = 2*log2(e),
// with C2 folded into the per-lane W1/b1 constants.
static __device__ __forceinline__ float edge_rsum_lds(int o0, int o1, int estart,
                                                      const float2* ep,
                                                      float w1x, float w1y, float b1j) {
  float S0 = 0.f, S1 = 0.f;
  int c = o0;
  for (; c + 1 < o1; c += 2) {
    float2 e0 = ep[c - estart];
    float2 e1 = ep[c + 1 - estart];
    float t0 = fmaf(e0.x, w1x, fmaf(e0.y, w1y, b1j));
    float t1 = fmaf(e1.x, w1x, fmaf(e1.y, w1y, b1j));
    S0 += RCPF(EXP2F(t0) + 1.0f);
    S1 += RCPF(EXP2F(t1) + 1.0f);
  }
  if (c < o1) {
    float2 e0 = ep[c - estart];
    float t0 = fmaf(e0.x, w1x, fmaf(e0.y, w1y, b1j));
    S0 += RCPF(EXP2F(t0) + 1.0f);
  }
  return S0 + S1;
}

static __device__ __forceinline__ float edge_rsum_glob(int o0, int o1,
                                                       const int2* edges8,
                                                       const float* conc,
                                                       float w1x, float w1y, float b1j) {
  float S = 0.f;
  for (int c = o0; c < o1; ++c) {
    int2 rec = edges8[c];
    float cc = conc[rec.x];
    float t0 = fmaf(cc, w1x, fmaf(__int_as_float(rec.y), w1y, b1j));
    S += RCPF(EXP2F(t0) + 1.0f);
  }
  return S;
}

__global__ __launch_bounds__(THREADS) void k_edge_mv(
    const int* __restrict__ off, const int2* __restrict__ edges8,
    const float* __restrict__ conc,
    const float* __restrict__ W1, const float* __restrict__ b1,
    const uint4* __restrict__ wfh, const uint4* __restrict__ wfl,
    const float* __restrict__ b2w3, const float* __restrict__ b3,
    const float* __restrict__ W4, const float* __restrict__ b4,
    const float* __restrict__ log_k, float* __restrict__ v_pre) {
  __shared__ int off_s[RXN_PER_BLK + 1];
  __shared__ float2 se[EDGE_CAP];
  __shared__ __align__(16) unsigned short thi[4][16][TPAD];  // 9.2 KB
  __shared__ __align__(16) unsigned short tlo[4][16][TPAD];  // 9.2 KB

  int tid = threadIdx.x;
  int lane = tid & 63;
  int wv = tid >> 6;
  int R0 = blockIdx.x * RXN_PER_BLK;

  for (int i = tid; i <= RXN_PER_BLK; i += THREADS) {
    int r = R0 + i;
    off_s[i] = off[r > N_RXN ? N_RXN : r];
  }
  __syncthreads();
  int estart = off_s[0];
  int nE = off_s[RXN_PER_BLK] - estart;
  bool fits = (nE <= EDGE_CAP);
  if (fits) {
    for (int i = tid; i < nE; i += THREADS) {
      int2 rec = edges8[estart + i];
      se[i] = make_float2(conc[rec.x], __int_as_float(rec.y));
    }
  }

  const float C2 = 2.8853900817779268f;  // 2*log2(e)
  float w1x = W1[lane] * C2, w1y = W1[64 + lane] * C2, b1j = b1[lane] * C2;

  int rbase = R0 + wv * 64;
  int o0l = off_s[wv * 64 + lane];
  int o1l = off_s[wv * 64 + lane + 1];

  int col = lane & 15, rowg = lane >> 4;

  // per-lane epilogue constants (tiny, L1/L2 hits)
  float w4c[4], bwc[4], b3c[4];
  #pragma unroll
  for (int jt = 0; jt < 4; ++jt) {
    int jj = jt * 16 + col;
    w4c[jt] = W4[jj]; bwc[jt] = b2w3[jj]; b3c[jt] = b3[jj];
  }
  float b40 = b4[0];

  __syncthreads();

  // opaque per-tile pointers: keep B-fragment loads inside the tile loop
  const uint4* wfh_v = wfh;
  const uint4* wfl_v = wfl;

  unsigned short* thw = &thi[wv][0][0];
  unsigned short* tlw = &tlo[wv][0][0];

  int o0 = bcast_i(o0l, 0);   // o0 of reaction i is o1 of reaction i-1: carry it
  #pragma clang loop unroll(disable)
  for (int tt = 0; tt < 4; ++tt) {
    asm volatile("" : "+v"(wfh_v), "+v"(wfl_v));
    int rt = rbase + tt * 16;
    // ---- edge phase for 16 reactions (lane = feature) ----
    #pragma clang loop unroll(disable)
    for (int i = 0; i < 16; ++i) {
      int li = tt * 16 + i;
      int o1 = bcast_i(o1l, li);
      float S = fits ? edge_rsum_lds(o0, o1, estart, se, w1x, w1y, b1j)
                     : edge_rsum_glob(o0, o1, edges8, conc, w1x, w1y, b1j);
      float T = (float)(o1 - o0) - 2.0f * S;   // out-of-range rxns: o0==o1 -> T=0
      unsigned short hi = bf16_rn(T);
      float hf = __uint_as_float(((unsigned)hi) << 16);
      thw[i * TPAD + lane] = hi;
      tlw[i * TPAD + lane] = bf16_rn(T - hf);
      o0 = o1;
    }
    // ---- MFMA phase: wave-local LDS RAW (compiler inserts lgkmcnt) ----
    bf16x8 ah[2], al[2];
    {
      int fo = col * TPAD + rowg * 8;       // u16 elements; TPAD=72 -> 9 uint4/row
      const uint4* ph = (const uint4*)thw;
      const uint4* pl = (const uint4*)tlw;
      ah[0] = __builtin_bit_cast(bf16x8, ph[fo >> 3]);
      ah[1] = __builtin_bit_cast(bf16x8, ph[(fo + 32) >> 3]);
      al[0] = __builtin_bit_cast(bf16x8, pl[fo >> 3]);
      al[1] = __builtin_bit_cast(bf16x8, pl[(fo + 32) >> 3]);
    }
    f32x4 acc[4];
    #pragma unroll
    for (int jt = 0; jt < 4; ++jt) acc[jt] = (f32x4){0.f, 0.f, 0.f, 0.f};
    #pragma unroll
    for (int jt = 0; jt < 4; ++jt) {
      #pragma unroll
      for (int ks = 0; ks < 2; ++ks) {
        int bidx = (ks * 4 + jt) * 64 + lane;
        bf16x8 bh = __builtin_bit_cast(bf16x8, wfh_v[bidx]);
        bf16x8 bl = __builtin_bit_cast(bf16x8, wfl_v[bidx]);
        acc[jt] = __builtin_amdgcn_mfma_f32_16x16x32_bf16(ah[ks], bh, acc[jt], 0, 0, 0);
        acc[jt] = __builtin_amdgcn_mfma_f32_16x16x32_bf16(ah[ks], bl, acc[jt], 0, 0, 0);
        acc[jt] = __builtin_amdgcn_mfma_f32_16x16x32_bf16(al[ks], bh, acc[jt], 0, 0, 0);
      }
    }
    // ---- epilogue for reactions rt .. rt+15 ----
    float nq[4];
    #pragma unroll
    for (int q = 0; q < 4; ++q) {
      int idx = tt * 16 + rowg * 4 + q + wv * 64;
      nq[q] = (float)(off_s[idx + 1] - off_s[idx]);
    }
    #pragma unroll
    for (int q = 0; q < 4; ++q) {
      float s = 0.f;
      #pragma unroll
      for (int jt = 0; jt < 4; ++jt) {
        float u = acc[jt][q] + nq[q] * bwc[jt] + b3c[jt];
        s += fast_tanh(u) * w4c[jt];
      }
      s += __shfl_xor(s, 1, 64);
      s += __shfl_xor(s, 2, 64);
      s += __shfl_xor(s, 4, 64);
      s += __shfl_xor(s, 8, 64);
      if (col == 0) {
        int r = rt + rowg * 4 + q;
        float lk = (r < N_RXN) ? log_k[r] : 0.f;
        float racc = s + b40;
        float k10 = __expf(lk * 2.3025850929940457f);
        float sp = (racc > 15.f) ? racc : __logf(1.f + __expf(racc));
        if (r < N_RXN) v_pre[r] = k10 * sp;
      }
    }
  }
}

// accumulate consumption totals per bin + fused met_scale
__global__ __launch_bounds__(512) void k_bins_sub(
    const int2* __restrict__ bins_sub, const int* __restrict__ bin_start,
    const int* __restrict__ bin_tot, const float* __restrict__ conc,
    float* __restrict__ met_scale) {
  __shared__ float acc[BINSZ];
  int j = blockIdx.x, t = threadIdx.x;
  for (int i = t; i < BINSZ; i += 512) acc[i] = 0.f;
  __syncthreads();
  int s0 = bin_start[j], n = bin_tot[j];
  for (int i = t; i < n; i += 512) {
    int2 rec = bins_sub[s0 + i];
    atomicAdd(&acc[rec.x & (BINSZ - 1)], __int_as_float(rec.y));  // LDS fp32 atomic
  }
  __syncthreads();
  int m0 = j * BINSZ;
  for (int i = t; i < BINSZ; i += 512) {
    int m = m0 + i;
    if (m < N_MET) {
      float tot = acc[i];
      met_scale[m] = (tot > 1e-12f) ? fminf(conc[m] / tot, 1.0f) : 1.0f;
    }
  }
}

// ---- k_rscale: per-rxn min over CSR slice (4 lanes/rxn), fused vfin write ----
__global__ __launch_bounds__(256) void k_rscale(
    const int* __restrict__ off, const int2* __restrict__ edges8,
    const float* __restrict__ met_scale, const float* __restrict__ v_pre,
    float* __restrict__ vfin) {
  __shared__ int soff[MV_RPB + 1];
  int tid = threadIdx.x, lane = tid & 63, w = tid >> 6;
  int B0 = blockIdx.x * MV_RPB;
  for (int i = tid; i <= MV_RPB; i += 256) {
    int r = B0 + i;
    soff[i] = off[r > N_RXN ? N_RXN : r];
  }
  __syncthreads();

  int rloc = w * 16 + (lane >> 2);
  int o0 = soff[rloc], o1 = soff[rloc + 1];
  float sc = 1.0f;
  for (int c = o0 + (lane & 3); c < o1; c += 4) {
    sc = fminf(sc, met_scale[edges8[c].x]);
  }
  sc = fminf(sc, __shfl_xor(sc, 1, 64));
  sc = fminf(sc, __shfl_xor(sc, 2, 64));
  if ((lane & 3) == 0) {
    int r = B0 + rloc;
    if (r < N_RXN) vfin[r] = v_pre[r] * sc;
  }
}

__global__ __launch_bounds__(512) void k_bins(const int2* __restrict__ bins,
                                              const int* __restrict__ bin_start,
                                              const int* __restrict__ bin_tot,
                                              float* __restrict__ dxdt) {
  __shared__ float acc[BINSZ];
  int j = blockIdx.x, t = threadIdx.x;
  for (int i = t; i < BINSZ; i += 512) acc[i] = 0.f;
  __syncthreads();
  int s0 = bin_start[j], n = bin_tot[j];
  for (int i = t; i < n; i += 512) {
    int2 rec = bins[s0 + i];
    atomicAdd(&acc[rec.x & (BINSZ - 1)], __int_as_float(rec.y));  // LDS fp32 atomic
  }
  __syncthreads();
  int m0 = j * BINSZ;
  for (int i = t; i < BINSZ; i += 512) {
    int m = m0 + i;
    if (m < N_MET) dxdt[m] = acc[i];
  }
}

extern "C" void kernel_launch(void* const* d_in, const int* in_sizes, int n_in,
                              void* d_out, int out_size, void* d_ws, size_t ws_size,
                              hipStream_t stream) {
  const float* x       = (const float*)d_in[0];
  const int*   met_sub = (const int*)d_in[1];
  const int*   rxn_sub = (const int*)d_in[2];
  const float* sto_sub = (const float*)d_in[3];
  const int*   met_all = (const int*)d_in[4];
  const int*   rxn_all = (const int*)d_in[5];
  const float* sto_all = (const float*)d_in[6];
  const float* W1    = (const float*)d_in[7];
  const float* b1    = (const float*)d_in[8];
  const float* W2    = (const float*)d_in[9];
  const float* b2    = (const float*)d_in[10];
  const float* W3    = (const float*)d_in[11];
  const float* b3    = (const float*)d_in[12];
  const float* W4    = (const float*)d_in[13];
  const float* b4    = (const float*)d_in[14];
  const float* log_k = (const float*)d_in[15];
  float* dxdt = (float*)d_out;

  char* ws = (char*)d_ws;
  size_t p = 0;
  auto alloc = [&](size_t bytes) -> void* {
    void* r = (void*)(ws + p);
    p += (bytes + 255) & ~(size_t)255;
    return r;
  };
  int*    off        = (int*)alloc(sizeof(int) * (N_RXN + 1));
  uint4*  wfh        = (uint4*)alloc(sizeof(uint4) * 512);
  uint4*  wfl        = (uint4*)alloc(sizeof(uint4) * 512);
  float*  b2w3       = (float*)alloc(sizeof(float) * 64);
  float*  v_pre      = (float*)alloc(sizeof(float) * N_RXN);
  float*  vfin       = (float*)alloc(sizeof(float) * N_RXN);
  float*  conc       = (float*)alloc(sizeof(float) * N_MET);
  float*  met_scale  = (float*)alloc(sizeof(float) * N_MET);
  int2*   edges8     = (int2*)alloc(sizeof(int2) * E_SUB);      // CSR {m, sto}
  int2*   bins_rxn   = (int2*)alloc(sizeof(int2) * E_SUB);      // rxn-binned staging
  int2*   bins_sub   = (int2*)alloc(sizeof(int2) * E_SUB);      // met-binned {k, val}
  int2*   bins       = (int2*)alloc(sizeof(int2) * E_ALL);      // met-binned {k, val}
  int*    rblk_cnt   = (int*)alloc(sizeof(int) * RNBINS * RPART_NBLK);
  int*    rblk_pref  = (int*)alloc(sizeof(int) * RNBINS * RPART_NBLK);
  int*    sblk_cnt   = (int*)alloc(sizeof(int) * NBINS * SPART_NBLK);
  int*    sblk_pref  = (int*)alloc(sizeof(int) * NBINS * SPART_NBLK);
  int*    blk_cnt    = (int*)alloc(sizeof(int) * NBINS * PART_NBLK);
  int*    blk_pref   = (int*)alloc(sizeof(int) * NBINS * PART_NBLK);
  int*    rbin_tot   = (int*)alloc(sizeof(int) * 512);
  int*    rbin_start = (int*)alloc(sizeof(int) * 512);
  int*    sbin_tot   = (int*)alloc(sizeof(int) * 512);
  int*    sbin_start = (int*)alloc(sizeof(int) * 512);
  int*    bin_tot    = (int*)alloc(sizeof(int) * 512);
  int*    bin_start  = (int*)alloc(sizeof(int) * 512);
  (void)in_sizes; (void)n_in; (void)out_size; (void)ws_size;

  // no global memsets needed: every buffer is fully written before it is read

  // fused: all 3 bin-count histograms + conc extraction + W23/b2w3 precompute
  k_bc3<<<RPART_NBLK + SPART_NBLK + PART_NBLK, 256, 0, stream>>>(
      rxn_sub, met_sub, met_all, x, conc, W2, W3, b2, wfh, wfl, b2w3,
      rblk_cnt, sblk_cnt, blk_cnt);
  // fused scans
  k_scan1all<<<RNBINS + NBINS + NBINS, 256, 0, stream>>>(
      rblk_cnt, rblk_pref, rbin_tot, sblk_cnt, sblk_pref, sbin_tot,
      blk_cnt, blk_pref, bin_tot);
  k_scan2all<<<3, 512, 0, stream>>>(rbin_tot, rbin_start, sbin_tot, sbin_start,
                                    bin_tot, bin_start);

  // CSR build (counting sort, no global atomics)
  k_rpart<<<RPART_NBLK, PTHREADS, 0, stream>>>(rxn_sub, met_sub, sto_sub,
                                               rblk_pref, rbin_start, bins_rxn);
  k_rbin<<<RNBINS, 512, 0, stream>>>(bins_rxn, rbin_start, rbin_tot, edges8, off);

  // fused MLP: edge tanh-sum + MFMA + epilogue -> v_pre (T stays on-CU)
  k_edge_mv<<<(N_RXN + RXN_PER_BLK - 1) / RXN_PER_BLK, THREADS, 0, stream>>>(
      off, edges8, conc, W1, b1, wfh, wfl, b2w3, b3, W4, b4, log_k, v_pre);

  // consumption totals -> met_scale (binned, fused scale)
  k_part_sub<<<SPART_NBLK, PTHREADS, 0, stream>>>(met_sub, rxn_sub, sto_sub, v_pre,
                                                  sblk_pref, sbin_start, bins_sub);
  k_bins_sub<<<NBINS, 512, 0, stream>>>(bins_sub, sbin_start, sbin_tot, conc, met_scale);

  // rxn scale + final v
  k_rscale<<<(N_RXN + MV_RPB - 1) / MV_RPB, 256, 0, stream>>>(
      off, edges8, met_scale, v_pre, vfin);

  // dxdt (binned)
  k_part<<<PART_NBLK, PTHREADS, 0, stream>>>(met_all, rxn_all, sto_all, vfin,
                                             blk_pref, bin_start, bins);
  k_bins<<<NBINS, 512, 0, stream>>>(bins, bin_start, bin_tot, dxdt);
}

// Round 5
// 428.493 us; speedup vs baseline: 1.0091x; 1.0091x over previous
//
#include <hip/hip_runtime.h>

#define N_MET 250000
#define N_RXN 500000
#define E_SUB 2000000
#define E_ALL 4000000
#define DT 0.01f

#define RXN_PER_BLK 256
#define THREADS 256
#define EDGE_CAP 1536   // k_edge_mv LDS staging cap; global fallback below
#define TPAD 72         // padded K for per-wave T tiles (64 + 8)

#define MV_RPB 64       // k_rscale reactions per block (4 waves x 16)

// ---- binning geometry ----
#define BINSZ 1024
#define NBINS ((N_MET + BINSZ - 1) / BINSZ)                 // 245
#define PART_EPB 4096
#define PTHREADS 512                                        // part_sorted block size
#define KPB (PART_EPB / PTHREADS)                           // 8 keys/thread
#define PART_NBLK ((E_ALL + PART_EPB - 1) / PART_EPB)       // 977
#define SPART_NBLK ((E_SUB + PART_EPB - 1) / PART_EPB)      // 489
#define RBINSZ 1024
#define RNBINS ((N_RXN + RBINSZ - 1) / RBINSZ)              // 489
#define RPART_NBLK ((E_SUB + PART_EPB - 1) / PART_EPB)      // 489
#define RBIN_CAP 6144   // Poisson(4096) + ~30 sigma; global fallback below

typedef int v4i __attribute__((ext_vector_type(4)));
typedef float v4f __attribute__((ext_vector_type(4)));
typedef short bf16x8 __attribute__((ext_vector_type(8)));
typedef float f32x4 __attribute__((ext_vector_type(4)));

// fast exp2 / rcp mapping straight to v_exp_f32 / v_rcp_f32
#if __has_builtin(__builtin_amdgcn_exp2f)
#define EXP2F(x) __builtin_amdgcn_exp2f(x)
#else
#define EXP2F(x) exp2f(x)
#endif
#if __has_builtin(__builtin_amdgcn_rcpf)
#define RCPF(x) __builtin_amdgcn_rcpf(x)
#else
#define RCPF(x) __fdividef(1.0f, (x))
#endif

static __device__ __forceinline__ float fast_tanh(float x) {
  float e = __expf(x + x);
  return 1.0f - __fdividef(2.0f, e + 1.0f);
}

static __device__ __forceinline__ int bcast_i(int v, int lane) {
  return __builtin_amdgcn_readlane(v, lane);
}

static __device__ __forceinline__ unsigned short bf16_rn(float f) {
  unsigned u = __float_as_uint(f);
  unsigned r = u + 0x7FFFu + ((u >> 16) & 1u);
  return (unsigned short)(r >> 16);
}

// hardware RNE f32->bf16 (both halves of result hold the same bf16)
static __device__ __forceinline__ unsigned cvt_bf16_pk(float f) {
  unsigned r;
  asm("v_cvt_pk_bf16_f32 %0, %1, %2" : "=v"(r) : "v"(f), "v"(f));
  return r;
}

// ==== fused: bin-counts for all 3 partitions + conc extraction + W23 precompute ====
__global__ __launch_bounds__(256) void k_bc3(
    const int* __restrict__ rxn_sub, const int* __restrict__ met_sub,
    const int* __restrict__ met_all,
    const float* __restrict__ x, float* __restrict__ conc,
    const float* __restrict__ W2, const float* __restrict__ W3,
    const float* __restrict__ b2,
    uint4* __restrict__ wfh, uint4* __restrict__ wfl, float* __restrict__ b2w3,
    int* __restrict__ rblk_cnt, int* __restrict__ sblk_cnt, int* __restrict__ blk_cnt) {
  __shared__ int cnt[RNBINS];   // max of {489, 245, 245}
  int b = blockIdx.x, t = threadIdx.x;
  const int* keys; int nkeys, nblk, nb, bl; int* out;
  if (b < RPART_NBLK) {
    keys = rxn_sub; nkeys = E_SUB; nblk = RPART_NBLK; nb = RNBINS; out = rblk_cnt; bl = b;
    if (b < 2) {
      // ---- k_pre: MFMA B-fragments of W23 = W2@W3 (bf16 hi/lo) and b2@W3 ----
      int tid = b * 256 + t;
      if (tid < 512) {
        int lane = tid & 63, jt = (tid >> 6) & 3, ks = tid >> 8;
        int jj = jt * 16 + (lane & 15);
        unsigned short h[8], l[8];
        #pragma unroll
        for (int q = 0; q < 8; ++q) {
          int kk = ks * 32 + (lane >> 4) * 8 + q;
          float w = 0.f;
          #pragma unroll
          for (int m = 0; m < 32; ++m) w = fmaf(W2[kk * 32 + m], W3[m * 64 + jj], w);
          h[q] = bf16_rn(w);
          float hf = __uint_as_float(((unsigned)h[q]) << 16);
          l[q] = bf16_rn(w - hf);
        }
        uint4 H, L;
        H.x = (unsigned)h[0] | ((unsigned)h[1] << 16);
        H.y = (unsigned)h[2] | ((unsigned)h[3] << 16);
        H.z = (unsigned)h[4] | ((unsigned)h[5] << 16);
        H.w = (unsigned)h[6] | ((unsigned)h[7] << 16);
        L.x = (unsigned)l[0] | ((unsigned)l[1] << 16);
        L.y = (unsigned)l[2] | ((unsigned)l[3] << 16);
        L.z = (unsigned)l[4] | ((unsigned)l[5] << 16);
        L.w = (unsigned)l[6] | ((unsigned)l[7] << 16);
        int idx = (ks * 4 + jt) * 64 + lane;
        wfh[idx] = H; wfl[idx] = L;
      }
      if (tid < 64) {
        float s = 0.f;
        #pragma unroll
        for (int m = 0; m < 32; ++m) s = fmaf(b2[m], W3[m * 64 + tid], s);
        b2w3[tid] = s;
      }
    }
  } else if (b < RPART_NBLK + SPART_NBLK) {
    keys = met_sub; nkeys = E_SUB; nblk = SPART_NBLK; nb = NBINS; out = sblk_cnt;
    bl = b - RPART_NBLK;
  } else {
    keys = met_all; nkeys = E_ALL; nblk = PART_NBLK; nb = NBINS; out = blk_cnt;
    bl = b - RPART_NBLK - SPART_NBLK;
    int m = bl * 256 + t;
    if (m < N_MET) conc[m] = __builtin_nontemporal_load(x + m * 8 + 3);
  }
  for (int i = t; i < nb; i += 256) cnt[i] = 0;
  __syncthreads();
  int base = bl * PART_EPB;
  #pragma unroll
  for (int i = 0; i < PART_EPB / 256; ++i) {
    int e = base + i * 256 + t;
    if (e < nkeys) atomicAdd(&cnt[__builtin_nontemporal_load(keys + e) >> 10], 1);
  }
  __syncthreads();
  for (int i = t; i < nb; i += 256) out[i * nblk + bl] = cnt[i];
}

// ==== fused scans ====
static __device__ __forceinline__ void scan1_body(int* ss,
    const int* __restrict__ blk_cnt, int* __restrict__ blk_pref,
    int* __restrict__ bin_tot, int nblk, int j) {
  int t = threadIdx.x;
  int carry = 0;
  for (int c = 0; c < nblk; c += 256) {
    int idx = c + t;
    int v = (idx < nblk) ? blk_cnt[j * nblk + idx] : 0;
    ss[t] = v; __syncthreads();
    for (int d = 1; d < 256; d <<= 1) {
      int a = (t >= d) ? ss[t - d] : 0;
      __syncthreads();
      ss[t] += a;
      __syncthreads();
    }
    if (idx < nblk) blk_pref[j * nblk + idx] = carry + ss[t] - v;
    carry += ss[255];
    __syncthreads();
  }
  if (t == 0) bin_tot[j] = carry;
}

__global__ __launch_bounds__(256) void k_scan1all(
    const int* __restrict__ rblk_cnt, int* __restrict__ rblk_pref, int* __restrict__ rbin_tot,
    const int* __restrict__ sblk_cnt, int* __restrict__ sblk_pref, int* __restrict__ sbin_tot,
    const int* __restrict__ blk_cnt, int* __restrict__ blk_pref, int* __restrict__ bin_tot) {
  __shared__ int ss[256];
  int b = blockIdx.x;
  if (b < RNBINS)
    scan1_body(ss, rblk_cnt, rblk_pref, rbin_tot, RPART_NBLK, b);
  else if (b < RNBINS + NBINS)
    scan1_body(ss, sblk_cnt, sblk_pref, sbin_tot, SPART_NBLK, b - RNBINS);
  else
    scan1_body(ss, blk_cnt, blk_pref, bin_tot, PART_NBLK, b - RNBINS - NBINS);
}

__global__ __launch_bounds__(512) void k_scan2all(
    const int* __restrict__ rbin_tot, int* __restrict__ rbin_start,
    const int* __restrict__ sbin_tot, int* __restrict__ sbin_start,
    const int* __restrict__ bin_tot, int* __restrict__ bin_start) {
  __shared__ int ss[512];
  const int* tot; int* st; int n;
  if (blockIdx.x == 0)      { tot = rbin_tot; st = rbin_start; n = RNBINS; }
  else if (blockIdx.x == 1) { tot = sbin_tot; st = sbin_start; n = NBINS; }
  else                      { tot = bin_tot;  st = bin_start;  n = NBINS; }
  int t = threadIdx.x;
  int v = (t < n) ? tot[t] : 0;
  ss[t] = v; __syncthreads();
  for (int d = 1; d < 512; d <<= 1) {
    int a = (t >= d) ? ss[t - d] : 0;
    __syncthreads();
    ss[t] += a;
    __syncthreads();
  }
  if (t < n) st[t] = ss[t] - v;
}

// ==== block-locally-sorted partition: records leave as contiguous bursts ====
// 512 threads, 8 keys/thread. PACK=true: rec.x carries the full key (bin = rec.x>>10),
// so the binb[] side-array is eliminated (saves 8 KB LDS -> 4 blocks/CU).
template <int NB, bool PACK, typename MakeRec>
static __device__ __forceinline__ void part_sorted(
    const int* __restrict__ keys, int nkeys, int nblk,
    const int* __restrict__ blk_pref, const int* __restrict__ bin_start,
    int2* __restrict__ out, MakeRec make) {
  __shared__ int2 ordered[PART_EPB];                        // 32 KB
  __shared__ unsigned short binb[PACK ? 1 : PART_EPB];      // 8 KB only if !PACK
  __shared__ int cnt[NB];
  __shared__ int gofs[NB];
  __shared__ int ss[PTHREADS];
  int b = blockIdx.x, t = threadIdx.x;
  for (int i = t; i < NB; i += PTHREADS) cnt[i] = 0;
  __syncthreads();
  int base = b * PART_EPB;
  int kbuf[KPB];
  #pragma unroll
  for (int i = 0; i < KPB; ++i) {
    int e = base + i * PTHREADS + t;
    kbuf[i] = (e < nkeys) ? __builtin_nontemporal_load(keys + e) : -1;
    if (kbuf[i] >= 0) atomicAdd(&cnt[kbuf[i] >> 10], 1);
  }
  __syncthreads();
  // single-chunk scan (NB <= PTHREADS); cnt becomes cursor, gofs = global - lstart
  int v = (t < NB) ? cnt[t] : 0;
  ss[t] = v; __syncthreads();
  for (int d = 1; d < PTHREADS; d <<= 1) {
    int a = (t >= d) ? ss[t - d] : 0;
    __syncthreads();
    ss[t] += a;
    __syncthreads();
  }
  int nloc = ss[PTHREADS - 1];
  if (t < NB) {
    int ls = ss[t] - v;
    cnt[t] = ls;  // becomes cursor
    gofs[t] = bin_start[t] + blk_pref[t * nblk + b] - ls;
  }
  __syncthreads();
  // pass B: place records bin-ordered in LDS
  #pragma unroll
  for (int i = 0; i < KPB; ++i) {
    int k = kbuf[i];
    if (k >= 0) {
      int e = base + i * PTHREADS + t;
      int bin = k >> 10;
      int2 rec = make(e, k);
      int pos = atomicAdd(&cnt[bin], 1);  // LDS atomic
      ordered[pos] = rec;
      if (!PACK) binb[pos] = (unsigned short)bin;
    }
  }
  __syncthreads();
  // pass C: ordered, coalesced burst copy
  for (int i = t; i < nloc; i += PTHREADS) {
    int2 rec = ordered[i];
    int bin = PACK ? (int)(((unsigned)rec.x) >> 10) : (int)binb[i];
    out[gofs[bin] + i] = rec;
  }
}

// CSR partition: packed {rloc:10|m:18, sto} by rxn-bin (no spare bits -> binb path)
__global__ __launch_bounds__(PTHREADS) void k_rpart(
    const int* __restrict__ rxn_sub, const int* __restrict__ met_sub,
    const float* __restrict__ sto_sub,
    const int* __restrict__ blk_pref, const int* __restrict__ bin_start,
    int2* __restrict__ bins_rxn) {
  part_sorted<RNBINS, false>(rxn_sub, E_SUB, RPART_NBLK, blk_pref, bin_start, bins_rxn,
    [=] __device__ (int e, int k) {
      int m = __builtin_nontemporal_load(met_sub + e);
      float st = __builtin_nontemporal_load(sto_sub + e);
      int2 rec; rec.x = ((k & (RBINSZ - 1)) << 18) | m; rec.y = __float_as_int(st);
      return rec;
    });
}

// consumption partition: {k(full met idx), sto*v_pre[r]*DT} by met-bin
__global__ __launch_bounds__(PTHREADS) void k_part_sub(
    const int* __restrict__ met_sub, const int* __restrict__ rxn_sub,
    const float* __restrict__ sto_sub, const float* __restrict__ v_pre,
    const int* __restrict__ blk_pref, const int* __restrict__ bin_start,
    int2* __restrict__ bins_sub) {
  part_sorted<NBINS, true>(met_sub, E_SUB, SPART_NBLK, blk_pref, bin_start, bins_sub,
    [=] __device__ (int e, int k) {
      int r = __builtin_nontemporal_load(rxn_sub + e);
      float st = __builtin_nontemporal_load(sto_sub + e);
      float val = st * v_pre[r] * DT;
      int2 rec; rec.x = k; rec.y = __float_as_int(val);
      return rec;
    });
}

// dxdt partition: {k(full met idx), sto*vfin[r]} by met-bin
__global__ __launch_bounds__(PTHREADS) void k_part(
    const int* __restrict__ met_all, const int* __restrict__ rxn_all,
    const float* __restrict__ sto_all, const float* __restrict__ vfin,
    const int* __restrict__ blk_pref, const int* __restrict__ bin_start,
    int2* __restrict__ bins) {
  part_sorted<NBINS, true>(met_all, E_ALL, PART_NBLK, blk_pref, bin_start, bins,
    [=] __device__ (int e, int k) {
      int r = __builtin_nontemporal_load(rxn_all + e);
      float st = __builtin_nontemporal_load(sto_all + e);
      float val = st * vfin[r];
      int2 rec; rec.x = k; rec.y = __float_as_int(val);
      return rec;
    });
}

// ==== CSR per-bin local sort -> edges8 CSR order + off[] ====
__global__ __launch_bounds__(256) void k_rbin(
    const int2* __restrict__ bins_rxn, const int* __restrict__ rbin_start,
    const int* __restrict__ rbin_tot, int2* __restrict__ edges8, int* __restrict__ off) {
  __shared__ int2 stage[RBIN_CAP];   // 48 KB
  __shared__ int lcnt[RBINSZ];
  __shared__ int lcur[RBINSZ];
  __shared__ int ss[256];
  int j = blockIdx.x, t = threadIdx.x;
  int base = rbin_start[j], n = rbin_tot[j];
  for (int i = t; i < RBINSZ; i += 256) lcnt[i] = 0;
  __syncthreads();
  bool fits = (n <= RBIN_CAP);
  if (fits) {
    for (int i = t; i < n; i += 256) {
      int2 rec = bins_rxn[base + i];
      stage[i] = rec;
      atomicAdd(&lcnt[((unsigned)rec.x) >> 18], 1);
    }
  } else {
    for (int i = t; i < n; i += 256) {
      int2 rec = bins_rxn[base + i];
      atomicAdd(&lcnt[((unsigned)rec.x) >> 18], 1);
    }
  }
  __syncthreads();
  int s0 = lcnt[4 * t], s1 = lcnt[4 * t + 1], s2 = lcnt[4 * t + 2], s3 = lcnt[4 * t + 3];
  int tsum = s0 + s1 + s2 + s3;
  ss[t] = tsum; __syncthreads();
  for (int d = 1; d < 256; d <<= 1) {
    int a = (t >= d) ? ss[t - d] : 0;
    __syncthreads();
    ss[t] += a;
    __syncthreads();
  }
  int run = ss[t] - tsum;
  lcur[4 * t] = run;
  lcur[4 * t + 1] = run + s0;
  lcur[4 * t + 2] = run + s0 + s1;
  lcur[4 * t + 3] = run + s0 + s1 + s2;
  __syncthreads();
  int R0 = j * RBINSZ;
  for (int rl = t; rl < RBINSZ; rl += 256) {
    int r = R0 + rl;
    if (r < N_RXN) off[r] = base + lcur[rl];
  }
  if (j == 0 && t == 0) off[N_RXN] = E_SUB;
  __syncthreads();
  if (fits) {
    for (int i = t; i < n; i += 256) {
      int2 rec = stage[i];
      int pos = atomicAdd(&lcur[((unsigned)rec.x) >> 18], 1);
      int2 out; out.x = rec.x & 0x3FFFF; out.y = rec.y;
      edges8[base + pos] = out;
    }
  } else {
    for (int i = t; i < n; i += 256) {
      int2 rec = bins_rxn[base + i];
      int pos = atomicAdd(&lcur[((unsigned)rec.x) >> 18], 1);
      int2 out; out.x = rec.x & 0x3FFFF; out.y = rec.y;
      edges8[base + pos] = out;
    }
  }
}

// ---- k_edge_mv: fused edge tanh-sum + MFMA (T never leaves the CU) ----
// Math: sum_e tanh(x_e) = n - 2 * sum_e 1/(1 + exp2(C2*x_e)), C2 = 2*log2(e),
// with C2 folded into the per-lane W1/b1 constants.
// Edge loop is 4-wide with clamped indices + predicated accumulate: a typical
// degree-4 reaction completes in ONE iteration with 4 independent latency chains.
static __device__ __forceinline__ float edge_rsum_lds(int o0, int o1, int estart,
                                                      const float2* ep,
                                                      float w1x, float w1y, float b1j) {
  int n = o1 - o0;
  const float2* p = ep + (o0 - estart);
  float S0 = 0.f, S1 = 0.f, S2 = 0.f, S3 = 0.f;
  for (int c = 0; c < n; c += 4) {
    int n1 = n - 1;
    int i1 = (c + 1 < n1) ? c + 1 : n1;
    int i2 = (c + 2 < n1) ? c + 2 : n1;
    int i3 = (c + 3 < n1) ? c + 3 : n1;
    float2 e0 = p[c], e1 = p[i1], e2 = p[i2], e3 = p[i3];
    float r0 = RCPF(EXP2F(fmaf(e0.x, w1x, fmaf(e0.y, w1y, b1j))) + 1.0f);
    float r1 = RCPF(EXP2F(fmaf(e1.x, w1x, fmaf(e1.y, w1y, b1j))) + 1.0f);
    float r2 = RCPF(EXP2F(fmaf(e2.x, w1x, fmaf(e2.y, w1y, b1j))) + 1.0f);
    float r3 = RCPF(EXP2F(fmaf(e3.x, w1x, fmaf(e3.y, w1y, b1j))) + 1.0f);
    S0 += r0;
    S1 += (c + 1 < n) ? r1 : 0.f;
    S2 += (c + 2 < n) ? r2 : 0.f;
    S3 += (c + 3 < n) ? r3 : 0.f;
  }
  return (S0 + S1) + (S2 + S3);
}

static __device__ __forceinline__ float edge_rsum_glob(int o0, int o1,
                                                       const int2* edges8,
                                                       const float* conc,
                                                       float w1x, float w1y, float b1j) {
  float S = 0.f;
  for (int c = o0; c < o1; ++c) {
    int2 rec = edges8[c];
    float cc = conc[rec.x];
    float t0 = fmaf(cc, w1x, fmaf(__int_as_float(rec.y), w1y, b1j));
    S += RCPF(EXP2F(t0) + 1.0f);
  }
  return S;
}

__global__ __launch_bounds__(THREADS) void k_edge_mv(
    const int* __restrict__ off, const int2* __restrict__ edges8,
    const float* __restrict__ conc,
    const float* __restrict__ W1, const float* __restrict__ b1,
    const uint4* __restrict__ wfh, const uint4* __restrict__ wfl,
    const float* __restrict__ b2w3, const float* __restrict__ b3,
    const float* __restrict__ W4, const float* __restrict__ b4,
    const float* __restrict__ log_k, float* __restrict__ v_pre) {
  __shared__ int off_s[RXN_PER_BLK + 1];
  __shared__ float2 se[EDGE_CAP];
  __shared__ __align__(16) unsigned short thi[4][16][TPAD];  // 9.2 KB
  __shared__ __align__(16) unsigned short tlo[4][16][TPAD];  // 9.2 KB

  int tid = threadIdx.x;
  int lane = tid & 63;
  int wv = tid >> 6;
  int R0 = blockIdx.x * RXN_PER_BLK;

  for (int i = tid; i <= RXN_PER_BLK; i += THREADS) {
    int r = R0 + i;
    off_s[i] = off[r > N_RXN ? N_RXN : r];
  }
  __syncthreads();
  int estart = off_s[0];
  int nE = off_s[RXN_PER_BLK] - estart;
  bool fits = (nE <= EDGE_CAP);
  if (fits) {
    for (int i = tid; i < nE; i += THREADS) {
      int2 rec = edges8[estart + i];
      se[i] = make_float2(conc[rec.x], __int_as_float(rec.y));
    }
  }

  const float C2 = 2.8853900817779268f;  // 2*log2(e)
  float w1x = W1[lane] * C2, w1y = W1[64 + lane] * C2, b1j = b1[lane] * C2;

  int rbase = R0 + wv * 64;
  int o0l = off_s[wv * 64 + lane];
  int o1l = off_s[wv * 64 + lane + 1];

  int col = lane & 15, rowg = lane >> 4;

  // per-lane epilogue constants, prescaled for the exp2-form tanh:
  // s = sum_jt w4*tanh(u) = sw4 + sum_jt (-2*w4)*rcp(exp2(C2*u)+1)
  float w4n[4], bwc2[4], b3c2[4];
  float sw4 = 0.f;
  #pragma unroll
  for (int jt = 0; jt < 4; ++jt) {
    int jj = jt * 16 + col;
    float w4v = W4[jj];
    sw4 += w4v;
    w4n[jt] = -2.0f * w4v;
    bwc2[jt] = b2w3[jj] * C2;
    b3c2[jt] = b3[jj] * C2;
  }
  float b40 = b4[0];

  __syncthreads();

  // opaque per-tile pointers: keep B-fragment loads inside the tile loop
  const uint4* wfh_v = wfh;
  const uint4* wfl_v = wfl;

  unsigned short* thw = &thi[wv][0][0];
  unsigned short* tlw = &tlo[wv][0][0];

  int o0 = bcast_i(o0l, 0);   // o0 of reaction i is o1 of reaction i-1: carry it
  #pragma clang loop unroll(disable)
  for (int tt = 0; tt < 4; ++tt) {
    asm volatile("" : "+v"(wfh_v), "+v"(wfl_v));
    int rt = rbase + tt * 16;
    // ---- edge phase for 16 reactions (lane = feature) ----
    #pragma clang loop unroll(disable)
    for (int i = 0; i < 16; ++i) {
      int li = tt * 16 + i;
      int o1 = bcast_i(o1l, li);
      float S = fits ? edge_rsum_lds(o0, o1, estart, se, w1x, w1y, b1j)
                     : edge_rsum_glob(o0, o1, edges8, conc, w1x, w1y, b1j);
      float T = (float)(o1 - o0) - 2.0f * S;   // out-of-range rxns: o0==o1 -> T=0
      unsigned hp = cvt_bf16_pk(T);            // RNE, == bf16_rn
      thw[i * TPAD + lane] = (unsigned short)hp;
      float tl = T - __uint_as_float(hp << 16);
      unsigned lp = cvt_bf16_pk(tl);
      tlw[i * TPAD + lane] = (unsigned short)lp;
      o0 = o1;
    }
    // ---- MFMA phase: wave-local LDS RAW (compiler inserts lgkmcnt) ----
    bf16x8 ah[2], al[2];
    {
      int fo = col * TPAD + rowg * 8;       // u16 elements; TPAD=72 -> 9 uint4/row
      const uint4* ph = (const uint4*)thw;
      const uint4* pl = (const uint4*)tlw;
      ah[0] = __builtin_bit_cast(bf16x8, ph[fo >> 3]);
      ah[1] = __builtin_bit_cast(bf16x8, ph[(fo + 32) >> 3]);
      al[0] = __builtin_bit_cast(bf16x8, pl[fo >> 3]);
      al[1] = __builtin_bit_cast(bf16x8, pl[(fo + 32) >> 3]);
    }
    f32x4 acc[4];
    #pragma unroll
    for (int jt = 0; jt < 4; ++jt) acc[jt] = (f32x4){0.f, 0.f, 0.f, 0.f};
    #pragma unroll
    for (int jt = 0; jt < 4; ++jt) {
      #pragma unroll
      for (int ks = 0; ks < 2; ++ks) {
        int bidx = (ks * 4 + jt) * 64 + lane;
        bf16x8 bh = __builtin_bit_cast(bf16x8, wfh_v[bidx]);
        bf16x8 bl = __builtin_bit_cast(bf16x8, wfl_v[bidx]);
        acc[jt] = __builtin_amdgcn_mfma_f32_16x16x32_bf16(ah[ks], bh, acc[jt], 0, 0, 0);
        acc[jt] = __builtin_amdgcn_mfma_f32_16x16x32_bf16(ah[ks], bl, acc[jt], 0, 0, 0);
        acc[jt] = __builtin_amdgcn_mfma_f32_16x16x32_bf16(al[ks], bh, acc[jt], 0, 0, 0);
      }
    }
    // ---- epilogue for reactions rt .. rt+15 ----
    float nq[4];
    #pragma unroll
    for (int q = 0; q < 4; ++q) {
      int idx = tt * 16 + rowg * 4 + q + wv * 64;
      nq[q] = (float)(off_s[idx + 1] - off_s[idx]);
    }
    #pragma unroll
    for (int q = 0; q < 4; ++q) {
      float s = sw4;
      #pragma unroll
      for (int jt = 0; jt < 4; ++jt) {
        float up = fmaf(C2, acc[jt][q], fmaf(nq[q], bwc2[jt], b3c2[jt]));
        float rr = RCPF(EXP2F(up) + 1.0f);
        s = fmaf(w4n[jt], rr, s);
      }
      s += __shfl_xor(s, 1, 64);
      s += __shfl_xor(s, 2, 64);
      s += __shfl_xor(s, 4, 64);
      s += __shfl_xor(s, 8, 64);
      if (col == 0) {
        int r = rt + rowg * 4 + q;
        float lk = (r < N_RXN) ? log_k[r] : 0.f;
        float racc = s + b40;
        float k10 = __expf(lk * 2.3025850929940457f);
        float sp = (racc > 15.f) ? racc : __logf(1.f + __expf(racc));
        if (r < N_RXN) v_pre[r] = k10 * sp;
      }
    }
  }
}

// accumulate consumption totals per bin + fused met_scale
__global__ __launch_bounds__(512) void k_bins_sub(
    const int2* __restrict__ bins_sub, const int* __restrict__ bin_start,
    const int* __restrict__ bin_tot, const float* __restrict__ conc,
    float* __restrict__ met_scale) {
  __shared__ float acc[BINSZ];
  int j = blockIdx.x, t = threadIdx.x;
  for (int i = t; i < BINSZ; i += 512) acc[i] = 0.f;
  __syncthreads();
  int s0 = bin_start[j], n = bin_tot[j];
  for (int i = t; i < n; i += 512) {
    int2 rec = bins_sub[s0 + i];
    atomicAdd(&acc[rec.x & (BINSZ - 1)], __int_as_float(rec.y));  // LDS fp32 atomic
  }
  __syncthreads();
  int m0 = j * BINSZ;
  for (int i = t; i < BINSZ; i += 512) {
    int m = m0 + i;
    if (m < N_MET) {
      float tot = acc[i];
      met_scale[m] = (tot > 1e-12f) ? fminf(conc[m] / tot, 1.0f) : 1.0f;
    }
  }
}

// ---- k_rscale: per-rxn min over CSR slice (4 lanes/rxn), fused vfin write ----
__global__ __launch_bounds__(256) void k_rscale(
    const int* __restrict__ off, const int2* __restrict__ edges8,
    const float* __restrict__ met_scale, const float* __restrict__ v_pre,
    float* __restrict__ vfin) {
  __shared__ int soff[MV_RPB + 1];
  int tid = threadIdx.x, lane = tid & 63, w = tid >> 6;
  int B0 = blockIdx.x * MV_RPB;
  for (int i = tid; i <= MV_RPB; i += 256) {
    int r = B0 + i;
    soff[i] = off[r > N_RXN ? N_RXN : r];
  }
  __syncthreads();

  int rloc = w * 16 + (lane >> 2);
  int o0 = soff[rloc], o1 = soff[rloc + 1];
  float sc = 1.0f;
  for (int c = o0 + (lane & 3); c < o1; c += 4) {
    sc = fminf(sc, met_scale[edges8[c].x]);
  }
  sc = fminf(sc, __shfl_xor(sc, 1, 64));
  sc = fminf(sc, __shfl_xor(sc, 2, 64));
  if ((lane & 3) == 0) {
    int r = B0 + rloc;
    if (r < N_RXN) vfin[r] = v_pre[r] * sc;
  }
}

__global__ __launch_bounds__(512) void k_bins(const int2* __restrict__ bins,
                                              const int* __restrict__ bin_start,
                                              const int* __restrict__ bin_tot,
                                              float* __restrict__ dxdt) {
  __shared__ float acc[BINSZ];
  int j = blockIdx.x, t = threadIdx.x;
  for (int i = t; i < BINSZ; i += 512) acc[i] = 0.f;
  __syncthreads();
  int s0 = bin_start[j], n = bin_tot[j];
  for (int i = t; i < n; i += 512) {
    int2 rec = bins[s0 + i];
    atomicAdd(&acc[rec.x & (BINSZ - 1)], __int_as_float(rec.y));  // LDS fp32 atomic
  }
  __syncthreads();
  int m0 = j * BINSZ;
  for (int i = t; i < BINSZ; i += 512) {
    int m = m0 + i;
    if (m < N_MET) dxdt[m] = acc[i];
  }
}

extern "C" void kernel_launch(void* const* d_in, const int* in_sizes, int n_in,
                              void* d_out, int out_size, void* d_ws, size_t ws_size,
                              hipStream_t stream) {
  const float* x       = (const float*)d_in[0];
  const int*   met_sub = (const int*)d_in[1];
  const int*   rxn_sub = (const int*)d_in[2];
  const float* sto_sub = (const float*)d_in[3];
  const int*   met_all = (const int*)d_in[4];
  const int*   rxn_all = (const int*)d_in[5];
  const float* sto_all = (const float*)d_in[6];
  const float* W1    = (const float*)d_in[7];
  const float* b1    = (const float*)d_in[8];
  const float* W2    = (const float*)d_in[9];
  const float* b2    = (const float*)d_in[10];
  const float* W3    = (const float*)d_in[11];
  const float* b3    = (const float*)d_in[12];
  const float* W4    = (const float*)d_in[13];
  const float* b4    = (const float*)d_in[14];
  const float* log_k = (const float*)d_in[15];
  float* dxdt = (float*)d_out;

  char* ws = (char*)d_ws;
  size_t p = 0;
  auto alloc = [&](size_t bytes) -> void* {
    void* r = (void*)(ws + p);
    p += (bytes + 255) & ~(size_t)255;
    return r;
  };
  int*    off        = (int*)alloc(sizeof(int) * (N_RXN + 1));
  uint4*  wfh        = (uint4*)alloc(sizeof(uint4) * 512);
  uint4*  wfl        = (uint4*)alloc(sizeof(uint4) * 512);
  float*  b2w3       = (float*)alloc(sizeof(float) * 64);
  float*  v_pre      = (float*)alloc(sizeof(float) * N_RXN);
  float*  vfin       = (float*)alloc(sizeof(float) * N_RXN);
  float*  conc       = (float*)alloc(sizeof(float) * N_MET);
  float*  met_scale  = (float*)alloc(sizeof(float) * N_MET);
  int2*   edges8     = (int2*)alloc(sizeof(int2) * E_SUB);      // CSR {m, sto}
  int2*   bins_rxn   = (int2*)alloc(sizeof(int2) * E_SUB);      // rxn-binned staging
  int2*   bins_sub   = (int2*)alloc(sizeof(int2) * E_SUB);      // met-binned {k, val}
  int2*   bins       = (int2*)alloc(sizeof(int2) * E_ALL);      // met-binned {k, val}
  int*    rblk_cnt   = (int*)alloc(sizeof(int) * RNBINS * RPART_NBLK);
  int*    rblk_pref  = (int*)alloc(sizeof(int) * RNBINS * RPART_NBLK);
  int*    sblk_cnt   = (int*)alloc(sizeof(int) * NBINS * SPART_NBLK);
  int*    sblk_pref  = (int*)alloc(sizeof(int) * NBINS * SPART_NBLK);
  int*    blk_cnt    = (int*)alloc(sizeof(int) * NBINS * PART_NBLK);
  int*    blk_pref   = (int*)alloc(sizeof(int) * NBINS * PART_NBLK);
  int*    rbin_tot   = (int*)alloc(sizeof(int) * 512);
  int*    rbin_start = (int*)alloc(sizeof(int) * 512);
  int*    sbin_tot   = (int*)alloc(sizeof(int) * 512);
  int*    sbin_start = (int*)alloc(sizeof(int) * 512);
  int*    bin_tot    = (int*)alloc(sizeof(int) * 512);
  int*    bin_start  = (int*)alloc(sizeof(int) * 512);
  (void)in_sizes; (void)n_in; (void)out_size; (void)ws_size;

  // no global memsets needed: every buffer is fully written before it is read

  // fused: all 3 bin-count histograms + conc extraction + W23/b2w3 precompute
  k_bc3<<<RPART_NBLK + SPART_NBLK + PART_NBLK, 256, 0, stream>>>(
      rxn_sub, met_sub, met_all, x, conc, W2, W3, b2, wfh, wfl, b2w3,
      rblk_cnt, sblk_cnt, blk_cnt);
  // fused scans
  k_scan1all<<<RNBINS + NBINS + NBINS, 256, 0, stream>>>(
      rblk_cnt, rblk_pref, rbin_tot, sblk_cnt, sblk_pref, sbin_tot,
      blk_cnt, blk_pref, bin_tot);
  k_scan2all<<<3, 512, 0, stream>>>(rbin_tot, rbin_start, sbin_tot, sbin_start,
                                    bin_tot, bin_start);

  // CSR build (counting sort, no global atomics)
  k_rpart<<<RPART_NBLK, PTHREADS, 0, stream>>>(rxn_sub, met_sub, sto_sub,
                                               rblk_pref, rbin_start, bins_rxn);
  k_rbin<<<RNBINS, 256, 0, stream>>>(bins_rxn, rbin_start, rbin_tot, edges8, off);

  // fused MLP: edge tanh-sum + MFMA + epilogue -> v_pre (T stays on-CU)
  k_edge_mv<<<(N_RXN + RXN_PER_BLK - 1) / RXN_PER_BLK, THREADS, 0, stream>>>(
      off, edges8, conc, W1, b1, wfh, wfl, b2w3, b3, W4, b4, log_k, v_pre);

  // consumption totals -> met_scale (binned, fused scale)
  k_part_sub<<<SPART_NBLK, PTHREADS, 0, stream>>>(met_sub, rxn_sub, sto_sub, v_pre,
                                                  sblk_pref, sbin_start, bins_sub);
  k_bins_sub<<<NBINS, 512, 0, stream>>>(bins_sub, sbin_start, sbin_tot, conc, met_scale);

  // rxn scale + final v
  k_rscale<<<(N_RXN + MV_RPB - 1) / MV_RPB, 256, 0, stream>>>(
      off, edges8, met_scale, v_pre, vfin);

  // dxdt (binned)
  k_part<<<PART_NBLK, PTHREADS, 0, stream>>>(met_all, rxn_all, sto_all, vfin,
                                             blk_pref, bin_start, bins);
  k_bins<<<NBINS, 512, 0, stream>>>(bins, bin_start, bin_tot, dxdt);
}

// Round 6
// 417.681 us; speedup vs baseline: 1.0353x; 1.0259x over previous
//
#include <hip/hip_runtime.h>

#define N_MET 250000
#define N_RXN 500000
#define E_SUB 2000000
#define E_ALL 4000000
#define DT 0.01f

#define RXN_PER_BLK 256
#define THREADS 256
#define EDGE_CAP 1536   // k_edge_mv LDS staging cap; global fallback below
#define TPAD 72         // padded K for per-wave T tiles (64 + 8)

#define MV_RPB 64       // k_rscale reactions per block (4 waves x 16)

// ---- binning geometry ----
#define BINSZ 1024
#define NBINS ((N_MET + BINSZ - 1) / BINSZ)                 // 245
#define PART_EPB 4096
#define PTHREADS 512                                        // part_sorted block size
#define KPB (PART_EPB / PTHREADS)                           // 8 keys/thread
#define PART_NBLK ((E_ALL + PART_EPB - 1) / PART_EPB)       // 977
#define SPART_NBLK ((E_SUB + PART_EPB - 1) / PART_EPB)      // 489
#define RBINSZ 1024
#define RNBINS ((N_RXN + RBINSZ - 1) / RBINSZ)              // 489
#define RPART_NBLK ((E_SUB + PART_EPB - 1) / PART_EPB)      // 489

typedef int v4i __attribute__((ext_vector_type(4)));
typedef float v4f __attribute__((ext_vector_type(4)));
typedef short bf16x8 __attribute__((ext_vector_type(8)));
typedef float f32x4 __attribute__((ext_vector_type(4)));

// fast exp2 / rcp mapping straight to v_exp_f32 / v_rcp_f32
#if __has_builtin(__builtin_amdgcn_exp2f)
#define EXP2F(x) __builtin_amdgcn_exp2f(x)
#else
#define EXP2F(x) exp2f(x)
#endif
#if __has_builtin(__builtin_amdgcn_rcpf)
#define RCPF(x) __builtin_amdgcn_rcpf(x)
#else
#define RCPF(x) __fdividef(1.0f, (x))
#endif

static __device__ __forceinline__ float fast_tanh(float x) {
  float e = __expf(x + x);
  return 1.0f - __fdividef(2.0f, e + 1.0f);
}

static __device__ __forceinline__ int bcast_i(int v, int lane) {
  return __builtin_amdgcn_readlane(v, lane);
}

static __device__ __forceinline__ unsigned short bf16_rn(float f) {
  unsigned u = __float_as_uint(f);
  unsigned r = u + 0x7FFFu + ((u >> 16) & 1u);
  return (unsigned short)(r >> 16);
}

// ==== fused: bin-counts for all 3 partitions + conc extraction + W23 precompute ====
__global__ __launch_bounds__(256) void k_bc3(
    const int* __restrict__ rxn_sub, const int* __restrict__ met_sub,
    const int* __restrict__ met_all,
    const float* __restrict__ x, float* __restrict__ conc,
    const float* __restrict__ W2, const float* __restrict__ W3,
    const float* __restrict__ b2,
    uint4* __restrict__ wfh, uint4* __restrict__ wfl, float* __restrict__ b2w3,
    int* __restrict__ rblk_cnt, int* __restrict__ sblk_cnt, int* __restrict__ blk_cnt) {
  __shared__ int cnt[RNBINS];   // max of {489, 245, 245}
  int b = blockIdx.x, t = threadIdx.x;
  const int* keys; int nkeys, nblk, nb, bl; int* out;
  if (b < RPART_NBLK) {
    keys = rxn_sub; nkeys = E_SUB; nblk = RPART_NBLK; nb = RNBINS; out = rblk_cnt; bl = b;
    if (b < 2) {
      // ---- k_pre: MFMA B-fragments of W23 = W2@W3 (bf16 hi/lo) and b2@W3 ----
      int tid = b * 256 + t;
      if (tid < 512) {
        int lane = tid & 63, jt = (tid >> 6) & 3, ks = tid >> 8;
        int jj = jt * 16 + (lane & 15);
        unsigned short h[8], l[8];
        #pragma unroll
        for (int q = 0; q < 8; ++q) {
          int kk = ks * 32 + (lane >> 4) * 8 + q;
          float w = 0.f;
          #pragma unroll
          for (int m = 0; m < 32; ++m) w = fmaf(W2[kk * 32 + m], W3[m * 64 + jj], w);
          h[q] = bf16_rn(w);
          float hf = __uint_as_float(((unsigned)h[q]) << 16);
          l[q] = bf16_rn(w - hf);
        }
        uint4 H, L;
        H.x = (unsigned)h[0] | ((unsigned)h[1] << 16);
        H.y = (unsigned)h[2] | ((unsigned)h[3] << 16);
        H.z = (unsigned)h[4] | ((unsigned)h[5] << 16);
        H.w = (unsigned)h[6] | ((unsigned)h[7] << 16);
        L.x = (unsigned)l[0] | ((unsigned)l[1] << 16);
        L.y = (unsigned)l[2] | ((unsigned)l[3] << 16);
        L.z = (unsigned)l[4] | ((unsigned)l[5] << 16);
        L.w = (unsigned)l[6] | ((unsigned)l[7] << 16);
        int idx = (ks * 4 + jt) * 64 + lane;
        wfh[idx] = H; wfl[idx] = L;
      }
      if (tid < 64) {
        float s = 0.f;
        #pragma unroll
        for (int m = 0; m < 32; ++m) s = fmaf(b2[m], W3[m * 64 + tid], s);
        b2w3[tid] = s;
      }
    }
  } else if (b < RPART_NBLK + SPART_NBLK) {
    keys = met_sub; nkeys = E_SUB; nblk = SPART_NBLK; nb = NBINS; out = sblk_cnt;
    bl = b - RPART_NBLK;
  } else {
    keys = met_all; nkeys = E_ALL; nblk = PART_NBLK; nb = NBINS; out = blk_cnt;
    bl = b - RPART_NBLK - SPART_NBLK;
    int m = bl * 256 + t;
    if (m < N_MET) conc[m] = __builtin_nontemporal_load(x + m * 8 + 3);
  }
  for (int i = t; i < nb; i += 256) cnt[i] = 0;
  __syncthreads();
  int base = bl * PART_EPB;
  #pragma unroll
  for (int i = 0; i < PART_EPB / 256; ++i) {
    int e = base + i * 256 + t;
    if (e < nkeys) atomicAdd(&cnt[__builtin_nontemporal_load(keys + e) >> 10], 1);
  }
  __syncthreads();
  for (int i = t; i < nb; i += 256) out[i * nblk + bl] = cnt[i];
}

// ==== fused scans ====
static __device__ __forceinline__ void scan1_body(int* ss,
    const int* __restrict__ blk_cnt, int* __restrict__ blk_pref,
    int* __restrict__ bin_tot, int nblk, int j) {
  int t = threadIdx.x;
  int carry = 0;
  for (int c = 0; c < nblk; c += 256) {
    int idx = c + t;
    int v = (idx < nblk) ? blk_cnt[j * nblk + idx] : 0;
    ss[t] = v; __syncthreads();
    for (int d = 1; d < 256; d <<= 1) {
      int a = (t >= d) ? ss[t - d] : 0;
      __syncthreads();
      ss[t] += a;
      __syncthreads();
    }
    if (idx < nblk) blk_pref[j * nblk + idx] = carry + ss[t] - v;
    carry += ss[255];
    __syncthreads();
  }
  if (t == 0) bin_tot[j] = carry;
}

__global__ __launch_bounds__(256) void k_scan1all(
    const int* __restrict__ rblk_cnt, int* __restrict__ rblk_pref, int* __restrict__ rbin_tot,
    const int* __restrict__ sblk_cnt, int* __restrict__ sblk_pref, int* __restrict__ sbin_tot,
    const int* __restrict__ blk_cnt, int* __restrict__ blk_pref, int* __restrict__ bin_tot) {
  __shared__ int ss[256];
  int b = blockIdx.x;
  if (b < RNBINS)
    scan1_body(ss, rblk_cnt, rblk_pref, rbin_tot, RPART_NBLK, b);
  else if (b < RNBINS + NBINS)
    scan1_body(ss, sblk_cnt, sblk_pref, sbin_tot, SPART_NBLK, b - RNBINS);
  else
    scan1_body(ss, blk_cnt, blk_pref, bin_tot, PART_NBLK, b - RNBINS - NBINS);
}

__global__ __launch_bounds__(512) void k_scan2all(
    const int* __restrict__ rbin_tot, int* __restrict__ rbin_start,
    const int* __restrict__ sbin_tot, int* __restrict__ sbin_start,
    const int* __restrict__ bin_tot, int* __restrict__ bin_start) {
  __shared__ int ss[512];
  const int* tot; int* st; int n;
  if (blockIdx.x == 0)      { tot = rbin_tot; st = rbin_start; n = RNBINS; }
  else if (blockIdx.x == 1) { tot = sbin_tot; st = sbin_start; n = NBINS; }
  else                      { tot = bin_tot;  st = bin_start;  n = NBINS; }
  int t = threadIdx.x;
  int v = (t < n) ? tot[t] : 0;
  ss[t] = v; __syncthreads();
  for (int d = 1; d < 512; d <<= 1) {
    int a = (t >= d) ? ss[t - d] : 0;
    __syncthreads();
    ss[t] += a;
    __syncthreads();
  }
  if (t < n) st[t] = ss[t] - v;
}

// ==== block-locally-sorted partition: records leave as contiguous bursts ====
// 512 threads, 8 keys/thread. PACK=true: rec.x carries the full key (bin = rec.x>>10),
// so the binb[] side-array is eliminated (saves 8 KB LDS -> 4 blocks/CU).
template <int NB, bool PACK, typename MakeRec>
static __device__ __forceinline__ void part_sorted(
    const int* __restrict__ keys, int nkeys, int nblk,
    const int* __restrict__ blk_pref, const int* __restrict__ bin_start,
    int2* __restrict__ out, MakeRec make) {
  __shared__ int2 ordered[PART_EPB];                        // 32 KB
  __shared__ unsigned short binb[PACK ? 1 : PART_EPB];      // 8 KB only if !PACK
  __shared__ int cnt[NB];
  __shared__ int gofs[NB];
  __shared__ int ss[PTHREADS];
  int b = blockIdx.x, t = threadIdx.x;
  for (int i = t; i < NB; i += PTHREADS) cnt[i] = 0;
  __syncthreads();
  int base = b * PART_EPB;
  int kbuf[KPB];
  #pragma unroll
  for (int i = 0; i < KPB; ++i) {
    int e = base + i * PTHREADS + t;
    kbuf[i] = (e < nkeys) ? __builtin_nontemporal_load(keys + e) : -1;
    if (kbuf[i] >= 0) atomicAdd(&cnt[kbuf[i] >> 10], 1);
  }
  __syncthreads();
  // single-chunk scan (NB <= PTHREADS); cnt becomes cursor, gofs = global - lstart
  int v = (t < NB) ? cnt[t] : 0;
  ss[t] = v; __syncthreads();
  for (int d = 1; d < PTHREADS; d <<= 1) {
    int a = (t >= d) ? ss[t - d] : 0;
    __syncthreads();
    ss[t] += a;
    __syncthreads();
  }
  int nloc = ss[PTHREADS - 1];
  if (t < NB) {
    int ls = ss[t] - v;
    cnt[t] = ls;  // becomes cursor
    gofs[t] = bin_start[t] + blk_pref[t * nblk + b] - ls;
  }
  __syncthreads();
  // pass B: place records bin-ordered in LDS
  #pragma unroll
  for (int i = 0; i < KPB; ++i) {
    int k = kbuf[i];
    if (k >= 0) {
      int e = base + i * PTHREADS + t;
      int bin = k >> 10;
      int2 rec = make(e, k);
      int pos = atomicAdd(&cnt[bin], 1);  // LDS atomic
      ordered[pos] = rec;
      if (!PACK) binb[pos] = (unsigned short)bin;
    }
  }
  __syncthreads();
  // pass C: ordered, coalesced burst copy
  for (int i = t; i < nloc; i += PTHREADS) {
    int2 rec = ordered[i];
    int bin = PACK ? (int)(((unsigned)rec.x) >> 10) : (int)binb[i];
    out[gofs[bin] + i] = rec;
  }
}

// CSR partition: packed {rloc:10|m:18, sto} by rxn-bin (no spare bits -> binb path)
__global__ __launch_bounds__(PTHREADS) void k_rpart(
    const int* __restrict__ rxn_sub, const int* __restrict__ met_sub,
    const float* __restrict__ sto_sub,
    const int* __restrict__ blk_pref, const int* __restrict__ bin_start,
    int2* __restrict__ bins_rxn) {
  part_sorted<RNBINS, false>(rxn_sub, E_SUB, RPART_NBLK, blk_pref, bin_start, bins_rxn,
    [=] __device__ (int e, int k) {
      int m = __builtin_nontemporal_load(met_sub + e);
      float st = __builtin_nontemporal_load(sto_sub + e);
      int2 rec; rec.x = ((k & (RBINSZ - 1)) << 18) | m; rec.y = __float_as_int(st);
      return rec;
    });
}

// consumption partition: {k(full met idx), sto*v_pre[r]*DT} by met-bin
__global__ __launch_bounds__(PTHREADS) void k_part_sub(
    const int* __restrict__ met_sub, const int* __restrict__ rxn_sub,
    const float* __restrict__ sto_sub, const float* __restrict__ v_pre,
    const int* __restrict__ blk_pref, const int* __restrict__ bin_start,
    int2* __restrict__ bins_sub) {
  part_sorted<NBINS, true>(met_sub, E_SUB, SPART_NBLK, blk_pref, bin_start, bins_sub,
    [=] __device__ (int e, int k) {
      int r = __builtin_nontemporal_load(rxn_sub + e);
      float st = __builtin_nontemporal_load(sto_sub + e);
      float val = st * v_pre[r] * DT;
      int2 rec; rec.x = k; rec.y = __float_as_int(val);
      return rec;
    });
}

// dxdt partition: {k(full met idx), sto*vfin[r]} by met-bin
__global__ __launch_bounds__(PTHREADS) void k_part(
    const int* __restrict__ met_all, const int* __restrict__ rxn_all,
    const float* __restrict__ sto_all, const float* __restrict__ vfin,
    const int* __restrict__ blk_pref, const int* __restrict__ bin_start,
    int2* __restrict__ bins) {
  part_sorted<NBINS, true>(met_all, E_ALL, PART_NBLK, blk_pref, bin_start, bins,
    [=] __device__ (int e, int k) {
      int r = __builtin_nontemporal_load(rxn_all + e);
      float st = __builtin_nontemporal_load(sto_all + e);
      float val = st * vfin[r];
      int2 rec; rec.x = k; rec.y = __float_as_int(val);
      return rec;
    });
}

// ==== CSR per-bin local sort -> edges8 CSR order + off[] ====
// 512 threads, NO LDS staging: each block's bins_rxn slice (~8 KB) was just
// written/streamed, so the pass-2 re-read is an L2 hit. Dropping the 48 KB
// stage buffer: LDS 57 KB -> 10 KB, occupancy 8 -> 32 waves/CU.
__global__ __launch_bounds__(512) void k_rbin(
    const int2* __restrict__ bins_rxn, const int* __restrict__ rbin_start,
    const int* __restrict__ rbin_tot, int2* __restrict__ edges8, int* __restrict__ off) {
  __shared__ int lcnt[RBINSZ];
  __shared__ int lcur[RBINSZ];
  __shared__ int ss[512];
  int j = blockIdx.x, t = threadIdx.x;
  int base = rbin_start[j], n = rbin_tot[j];
  for (int i = t; i < RBINSZ; i += 512) lcnt[i] = 0;
  __syncthreads();
  for (int i = t; i < n; i += 512) {
    int2 rec = bins_rxn[base + i];
    atomicAdd(&lcnt[((unsigned)rec.x) >> 18], 1);
  }
  __syncthreads();
  int s0 = lcnt[2 * t], s1 = lcnt[2 * t + 1];
  int tsum = s0 + s1;
  ss[t] = tsum; __syncthreads();
  for (int d = 1; d < 512; d <<= 1) {
    int a = (t >= d) ? ss[t - d] : 0;
    __syncthreads();
    ss[t] += a;
    __syncthreads();
  }
  int run = ss[t] - tsum;
  lcur[2 * t] = run;
  lcur[2 * t + 1] = run + s0;
  __syncthreads();
  int R0 = j * RBINSZ;
  for (int rl = t; rl < RBINSZ; rl += 512) {
    int r = R0 + rl;
    if (r < N_RXN) off[r] = base + lcur[rl];
  }
  if (j == 0 && t == 0) off[N_RXN] = E_SUB;
  __syncthreads();
  for (int i = t; i < n; i += 512) {
    int2 rec = bins_rxn[base + i];
    int pos = atomicAdd(&lcur[((unsigned)rec.x) >> 18], 1);
    int2 o; o.x = rec.x & 0x3FFFF; o.y = rec.y;
    edges8[base + pos] = o;
  }
}

// ---- k_edge_mv: fused edge tanh-sum + MFMA (T never leaves the CU) ----
// Math: sum_e tanh(x_e) = n - 2 * sum_e 1/(1 + exp2(C2*x_e)), C2 = 2*log2(e),
// with C2 folded into the per-lane W1/b1 constants.
static __device__ __forceinline__ float edge_rsum_lds(int o0, int o1, int estart,
                                                      const float2* ep,
                                                      float w1x, float w1y, float b1j) {
  float S0 = 0.f, S1 = 0.f;
  int c = o0;
  for (; c + 1 < o1; c += 2) {
    float2 e0 = ep[c - estart];
    float2 e1 = ep[c + 1 - estart];
    float t0 = fmaf(e0.x, w1x, fmaf(e0.y, w1y, b1j));
    float t1 = fmaf(e1.x, w1x, fmaf(e1.y, w1y, b1j));
    S0 += RCPF(EXP2F(t0) + 1.0f);
    S1 += RCPF(EXP2F(t1) + 1.0f);
  }
  if (c < o1) {
    float2 e0 = ep[c - estart];
    float t0 = fmaf(e0.x, w1x, fmaf(e0.y, w1y, b1j));
    S0 += RCPF(EXP2F(t0) + 1.0f);
  }
  return S0 + S1;
}

static __device__ __forceinline__ float edge_rsum_glob(int o0, int o1,
                                                       const int2* edges8,
                                                       const float* conc,
                                                       float w1x, float w1y, float b1j) {
  float S = 0.f;
  for (int c = o0; c < o1; ++c) {
    int2 rec = edges8[c];
    float cc = conc[rec.x];
    float t0 = fmaf(cc, w1x, fmaf(__int_as_float(rec.y), w1y, b1j));
    S += RCPF(EXP2F(t0) + 1.0f);
  }
  return S;
}

__global__ __launch_bounds__(THREADS) void k_edge_mv(
    const int* __restrict__ off, const int2* __restrict__ edges8,
    const float* __restrict__ conc,
    const float* __restrict__ W1, const float* __restrict__ b1,
    const uint4* __restrict__ wfh, const uint4* __restrict__ wfl,
    const float* __restrict__ b2w3, const float* __restrict__ b3,
    const float* __restrict__ W4, const float* __restrict__ b4,
    const float* __restrict__ log_k, float* __restrict__ v_pre) {
  __shared__ int off_s[RXN_PER_BLK + 1];
  __shared__ float2 se[EDGE_CAP];
  __shared__ __align__(16) unsigned short thi[4][16][TPAD];  // 9.2 KB
  __shared__ __align__(16) unsigned short tlo[4][16][TPAD];  // 9.2 KB

  int tid = threadIdx.x;
  int lane = tid & 63;
  int wv = tid >> 6;
  int R0 = blockIdx.x * RXN_PER_BLK;

  for (int i = tid; i <= RXN_PER_BLK; i += THREADS) {
    int r = R0 + i;
    off_s[i] = off[r > N_RXN ? N_RXN : r];
  }
  __syncthreads();
  int estart = off_s[0];
  int nE = off_s[RXN_PER_BLK] - estart;
  bool fits = (nE <= EDGE_CAP);
  if (fits) {
    for (int i = tid; i < nE; i += THREADS) {
      int2 rec = edges8[estart + i];
      se[i] = make_float2(conc[rec.x], __int_as_float(rec.y));
    }
  }

  const float C2 = 2.8853900817779268f;  // 2*log2(e)
  float w1x = W1[lane] * C2, w1y = W1[64 + lane] * C2, b1j = b1[lane] * C2;

  int rbase = R0 + wv * 64;
  int o0l = off_s[wv * 64 + lane];
  int o1l = off_s[wv * 64 + lane + 1];

  int col = lane & 15, rowg = lane >> 4;

  // per-lane epilogue constants (tiny, L1/L2 hits)
  float w4c[4], bwc[4], b3c[4];
  #pragma unroll
  for (int jt = 0; jt < 4; ++jt) {
    int jj = jt * 16 + col;
    w4c[jt] = W4[jj]; bwc[jt] = b2w3[jj]; b3c[jt] = b3[jj];
  }
  float b40 = b4[0];

  __syncthreads();

  // opaque per-tile pointers: keep B-fragment loads inside the tile loop
  const uint4* wfh_v = wfh;
  const uint4* wfl_v = wfl;

  unsigned short* thw = &thi[wv][0][0];
  unsigned short* tlw = &tlo[wv][0][0];

  int o0 = bcast_i(o0l, 0);   // o0 of reaction i is o1 of reaction i-1: carry it
  #pragma clang loop unroll(disable)
  for (int tt = 0; tt < 4; ++tt) {
    asm volatile("" : "+v"(wfh_v), "+v"(wfl_v));
    int rt = rbase + tt * 16;
    // ---- edge phase for 16 reactions (lane = feature) ----
    #pragma clang loop unroll(disable)
    for (int i = 0; i < 16; ++i) {
      int li = tt * 16 + i;
      int o1 = bcast_i(o1l, li);
      float S = fits ? edge_rsum_lds(o0, o1, estart, se, w1x, w1y, b1j)
                     : edge_rsum_glob(o0, o1, edges8, conc, w1x, w1y, b1j);
      float T = (float)(o1 - o0) - 2.0f * S;   // out-of-range rxns: o0==o1 -> T=0
      unsigned short hi = bf16_rn(T);
      float hf = __uint_as_float(((unsigned)hi) << 16);
      thw[i * TPAD + lane] = hi;
      tlw[i * TPAD + lane] = bf16_rn(T - hf);
      o0 = o1;
    }
    // ---- MFMA phase: wave-local LDS RAW (compiler inserts lgkmcnt) ----
    bf16x8 ah[2], al[2];
    {
      int fo = col * TPAD + rowg * 8;       // u16 elements; TPAD=72 -> 9 uint4/row
      const uint4* ph = (const uint4*)thw;
      const uint4* pl = (const uint4*)tlw;
      ah[0] = __builtin_bit_cast(bf16x8, ph[fo >> 3]);
      ah[1] = __builtin_bit_cast(bf16x8, ph[(fo + 32) >> 3]);
      al[0] = __builtin_bit_cast(bf16x8, pl[fo >> 3]);
      al[1] = __builtin_bit_cast(bf16x8, pl[(fo + 32) >> 3]);
    }
    f32x4 acc[4];
    #pragma unroll
    for (int jt = 0; jt < 4; ++jt) acc[jt] = (f32x4){0.f, 0.f, 0.f, 0.f};
    #pragma unroll
    for (int jt = 0; jt < 4; ++jt) {
      #pragma unroll
      for (int ks = 0; ks < 2; ++ks) {
        int bidx = (ks * 4 + jt) * 64 + lane;
        bf16x8 bh = __builtin_bit_cast(bf16x8, wfh_v[bidx]);
        bf16x8 bl = __builtin_bit_cast(bf16x8, wfl_v[bidx]);
        acc[jt] = __builtin_amdgcn_mfma_f32_16x16x32_bf16(ah[ks], bh, acc[jt], 0, 0, 0);
        acc[jt] = __builtin_amdgcn_mfma_f32_16x16x32_bf16(ah[ks], bl, acc[jt], 0, 0, 0);
        acc[jt] = __builtin_amdgcn_mfma_f32_16x16x32_bf16(al[ks], bh, acc[jt], 0, 0, 0);
      }
    }
    // ---- epilogue for reactions rt .. rt+15 ----
    float nq[4];
    #pragma unroll
    for (int q = 0; q < 4; ++q) {
      int idx = tt * 16 + rowg * 4 + q + wv * 64;
      nq[q] = (float)(off_s[idx + 1] - off_s[idx]);
    }
    #pragma unroll
    for (int q = 0; q < 4; ++q) {
      float s = 0.f;
      #pragma unroll
      for (int jt = 0; jt < 4; ++jt) {
        float u = acc[jt][q] + nq[q] * bwc[jt] + b3c[jt];
        s += fast_tanh(u) * w4c[jt];
      }
      s += __shfl_xor(s, 1, 64);
      s += __shfl_xor(s, 2, 64);
      s += __shfl_xor(s, 4, 64);
      s += __shfl_xor(s, 8, 64);
      if (col == 0) {
        int r = rt + rowg * 4 + q;
        float lk = (r < N_RXN) ? log_k[r] : 0.f;
        float racc = s + b40;
        float k10 = __expf(lk * 2.3025850929940457f);
        float sp = (racc > 15.f) ? racc : __logf(1.f + __expf(racc));
        if (r < N_RXN) v_pre[r] = k10 * sp;
      }
    }
  }
}

// accumulate consumption totals per bin + fused met_scale
__global__ __launch_bounds__(512) void k_bins_sub(
    const int2* __restrict__ bins_sub, const int* __restrict__ bin_start,
    const int* __restrict__ bin_tot, const float* __restrict__ conc,
    float* __restrict__ met_scale) {
  __shared__ float acc[BINSZ];
  int j = blockIdx.x, t = threadIdx.x;
  for (int i = t; i < BINSZ; i += 512) acc[i] = 0.f;
  __syncthreads();
  int s0 = bin_start[j], n = bin_tot[j];
  for (int i = t; i < n; i += 512) {
    int2 rec = bins_sub[s0 + i];
    atomicAdd(&acc[rec.x & (BINSZ - 1)], __int_as_float(rec.y));  // LDS fp32 atomic
  }
  __syncthreads();
  int m0 = j * BINSZ;
  for (int i = t; i < BINSZ; i += 512) {
    int m = m0 + i;
    if (m < N_MET) {
      float tot = acc[i];
      met_scale[m] = (tot > 1e-12f) ? fminf(conc[m] / tot, 1.0f) : 1.0f;
    }
  }
}

// ---- k_rscale: per-rxn min over CSR slice (4 lanes/rxn), fused vfin write ----
__global__ __launch_bounds__(256) void k_rscale(
    const int* __restrict__ off, const int2* __restrict__ edges8,
    const float* __restrict__ met_scale, const float* __restrict__ v_pre,
    float* __restrict__ vfin) {
  __shared__ int soff[MV_RPB + 1];
  int tid = threadIdx.x, lane = tid & 63, w = tid >> 6;
  int B0 = blockIdx.x * MV_RPB;
  for (int i = tid; i <= MV_RPB; i += 256) {
    int r = B0 + i;
    soff[i] = off[r > N_RXN ? N_RXN : r];
  }
  __syncthreads();

  int rloc = w * 16 + (lane >> 2);
  int o0 = soff[rloc], o1 = soff[rloc + 1];
  float sc = 1.0f;
  for (int c = o0 + (lane & 3); c < o1; c += 4) {
    sc = fminf(sc, met_scale[edges8[c].x]);
  }
  sc = fminf(sc, __shfl_xor(sc, 1, 64));
  sc = fminf(sc, __shfl_xor(sc, 2, 64));
  if ((lane & 3) == 0) {
    int r = B0 + rloc;
    if (r < N_RXN) vfin[r] = v_pre[r] * sc;
  }
}

__global__ __launch_bounds__(512) void k_bins(const int2* __restrict__ bins,
                                              const int* __restrict__ bin_start,
                                              const int* __restrict__ bin_tot,
                                              float* __restrict__ dxdt) {
  __shared__ float acc[BINSZ];
  int j = blockIdx.x, t = threadIdx.x;
  for (int i = t; i < BINSZ; i += 512) acc[i] = 0.f;
  __syncthreads();
  int s0 = bin_start[j], n = bin_tot[j];
  for (int i = t; i < n; i += 512) {
    int2 rec = bins[s0 + i];
    atomicAdd(&acc[rec.x & (BINSZ - 1)], __int_as_float(rec.y));  // LDS fp32 atomic
  }
  __syncthreads();
  int m0 = j * BINSZ;
  for (int i = t; i < BINSZ; i += 512) {
    int m = m0 + i;
    if (m < N_MET) dxdt[m] = acc[i];
  }
}

extern "C" void kernel_launch(void* const* d_in, const int* in_sizes, int n_in,
                              void* d_out, int out_size, void* d_ws, size_t ws_size,
                              hipStream_t stream) {
  const float* x       = (const float*)d_in[0];
  const int*   met_sub = (const int*)d_in[1];
  const int*   rxn_sub = (const int*)d_in[2];
  const float* sto_sub = (const float*)d_in[3];
  const int*   met_all = (const int*)d_in[4];
  const int*   rxn_all = (const int*)d_in[5];
  const float* sto_all = (const float*)d_in[6];
  const float* W1    = (const float*)d_in[7];
  const float* b1    = (const float*)d_in[8];
  const float* W2    = (const float*)d_in[9];
  const float* b2    = (const float*)d_in[10];
  const float* W3    = (const float*)d_in[11];
  const float* b3    = (const float*)d_in[12];
  const float* W4    = (const float*)d_in[13];
  const float* b4    = (const float*)d_in[14];
  const float* log_k = (const float*)d_in[15];
  float* dxdt = (float*)d_out;

  char* ws = (char*)d_ws;
  size_t p = 0;
  auto alloc = [&](size_t bytes) -> void* {
    void* r = (void*)(ws + p);
    p += (bytes + 255) & ~(size_t)255;
    return r;
  };
  int*    off        = (int*)alloc(sizeof(int) * (N_RXN + 1));
  uint4*  wfh        = (uint4*)alloc(sizeof(uint4) * 512);
  uint4*  wfl        = (uint4*)alloc(sizeof(uint4) * 512);
  float*  b2w3       = (float*)alloc(sizeof(float) * 64);
  float*  v_pre      = (float*)alloc(sizeof(float) * N_RXN);
  float*  vfin       = (float*)alloc(sizeof(float) * N_RXN);
  float*  conc       = (float*)alloc(sizeof(float) * N_MET);
  float*  met_scale  = (float*)alloc(sizeof(float) * N_MET);
  int2*   edges8     = (int2*)alloc(sizeof(int2) * E_SUB);      // CSR {m, sto}
  int2*   bins_rxn   = (int2*)alloc(sizeof(int2) * E_SUB);      // rxn-binned staging
  int2*   bins_sub   = (int2*)alloc(sizeof(int2) * E_SUB);      // met-binned {k, val}
  int2*   bins       = (int2*)alloc(sizeof(int2) * E_ALL);      // met-binned {k, val}
  int*    rblk_cnt   = (int*)alloc(sizeof(int) * RNBINS * RPART_NBLK);
  int*    rblk_pref  = (int*)alloc(sizeof(int) * RNBINS * RPART_NBLK);
  int*    sblk_cnt   = (int*)alloc(sizeof(int) * NBINS * SPART_NBLK);
  int*    sblk_pref  = (int*)alloc(sizeof(int) * NBINS * SPART_NBLK);
  int*    blk_cnt    = (int*)alloc(sizeof(int) * NBINS * PART_NBLK);
  int*    blk_pref   = (int*)alloc(sizeof(int) * NBINS * PART_NBLK);
  int*    rbin_tot   = (int*)alloc(sizeof(int) * 512);
  int*    rbin_start = (int*)alloc(sizeof(int) * 512);
  int*    sbin_tot   = (int*)alloc(sizeof(int) * 512);
  int*    sbin_start = (int*)alloc(sizeof(int) * 512);
  int*    bin_tot    = (int*)alloc(sizeof(int) * 512);
  int*    bin_start  = (int*)alloc(sizeof(int) * 512);
  (void)in_sizes; (void)n_in; (void)out_size; (void)ws_size;

  // no global memsets needed: every buffer is fully written before it is read

  // fused: all 3 bin-count histograms + conc extraction + W23/b2w3 precompute
  k_bc3<<<RPART_NBLK + SPART_NBLK + PART_NBLK, 256, 0, stream>>>(
      rxn_sub, met_sub, met_all, x, conc, W2, W3, b2, wfh, wfl, b2w3,
      rblk_cnt, sblk_cnt, blk_cnt);
  // fused scans
  k_scan1all<<<RNBINS + NBINS + NBINS, 256, 0, stream>>>(
      rblk_cnt, rblk_pref, rbin_tot, sblk_cnt, sblk_pref, sbin_tot,
      blk_cnt, blk_pref, bin_tot);
  k_scan2all<<<3, 512, 0, stream>>>(rbin_tot, rbin_start, sbin_tot, sbin_start,
                                    bin_tot, bin_start);

  // CSR build (counting sort, no global atomics)
  k_rpart<<<RPART_NBLK, PTHREADS, 0, stream>>>(rxn_sub, met_sub, sto_sub,
                                               rblk_pref, rbin_start, bins_rxn);
  k_rbin<<<RNBINS, 512, 0, stream>>>(bins_rxn, rbin_start, rbin_tot, edges8, off);

  // fused MLP: edge tanh-sum + MFMA + epilogue -> v_pre (T stays on-CU)
  k_edge_mv<<<(N_RXN + RXN_PER_BLK - 1) / RXN_PER_BLK, THREADS, 0, stream>>>(
      off, edges8, conc, W1, b1, wfh, wfl, b2w3, b3, W4, b4, log_k, v_pre);

  // consumption totals -> met_scale (binned, fused scale)
  k_part_sub<<<SPART_NBLK, PTHREADS, 0, stream>>>(met_sub, rxn_sub, sto_sub, v_pre,
                                                  sblk_pref, sbin_start, bins_sub);
  k_bins_sub<<<NBINS, 512, 0, stream>>>(bins_sub, sbin_start, sbin_tot, conc, met_scale);

  // rxn scale + final v
  k_rscale<<<(N_RXN + MV_RPB - 1) / MV_RPB, 256, 0, stream>>>(
      off, edges8, met_scale, v_pre, vfin);

  // dxdt (binned)
  k_part<<<PART_NBLK, PTHREADS, 0, stream>>>(met_all, rxn_all, sto_all, vfin,
                                             blk_pref, bin_start, bins);
  k_bins<<<NBINS, 512, 0, stream>>>(bins, bin_start, bin_tot, dxdt);
}

// Round 7
// 414.484 us; speedup vs baseline: 1.0432x; 1.0077x over previous
//
#include <hip/hip_runtime.h>

#define N_MET 250000
#define N_RXN 500000
#define E_SUB 2000000
#define E_ALL 4000000
#define DT 0.01f

#define RXN_PER_BLK 256
#define THREADS 256
#define EDGE_CAP 1536   // k_edge_mv LDS staging cap; global fallback below
#define TPAD 72         // padded K for per-wave T tiles (64 + 8)

#define MV_RPB 64       // k_rscale reactions per block (4 waves x 16)

// ---- binning geometry ----
#define BINSZ 1024
#define NBINS ((N_MET + BINSZ - 1) / BINSZ)                 // 245
#define PART_EPB 4096
#define PTHREADS 512                                        // part_sorted block size
#define KPB (PART_EPB / PTHREADS)                           // 8 keys/thread
#define PART_NBLK ((E_ALL + PART_EPB - 1) / PART_EPB)       // 977
#define SPART_NBLK ((E_SUB + PART_EPB - 1) / PART_EPB)      // 489
#define RBINSZ 1024
#define RNBINS ((N_RXN + RBINSZ - 1) / RBINSZ)              // 489
#define RPART_NBLK ((E_SUB + PART_EPB - 1) / PART_EPB)      // 489

typedef int v4i __attribute__((ext_vector_type(4)));
typedef float v4f __attribute__((ext_vector_type(4)));
typedef short bf16x8 __attribute__((ext_vector_type(8)));
typedef float f32x4 __attribute__((ext_vector_type(4)));

// fast exp2 / rcp mapping straight to v_exp_f32 / v_rcp_f32
#if __has_builtin(__builtin_amdgcn_exp2f)
#define EXP2F(x) __builtin_amdgcn_exp2f(x)
#else
#define EXP2F(x) exp2f(x)
#endif
#if __has_builtin(__builtin_amdgcn_rcpf)
#define RCPF(x) __builtin_amdgcn_rcpf(x)
#else
#define RCPF(x) __fdividef(1.0f, (x))
#endif

static __device__ __forceinline__ float fast_tanh(float x) {
  float e = __expf(x + x);
  return 1.0f - __fdividef(2.0f, e + 1.0f);
}

static __device__ __forceinline__ int bcast_i(int v, int lane) {
  return __builtin_amdgcn_readlane(v, lane);
}

static __device__ __forceinline__ unsigned short bf16_rn(float f) {
  unsigned u = __float_as_uint(f);
  unsigned r = u + 0x7FFFu + ((u >> 16) & 1u);
  return (unsigned short)(r >> 16);
}

// ==== fused: bin-counts for all 3 partitions + conc extraction + W23 precompute ====
__global__ __launch_bounds__(256) void k_bc3(
    const int* __restrict__ rxn_sub, const int* __restrict__ met_sub,
    const int* __restrict__ met_all,
    const float* __restrict__ x, float* __restrict__ conc,
    const float* __restrict__ W2, const float* __restrict__ W3,
    const float* __restrict__ b2,
    uint4* __restrict__ wfh, uint4* __restrict__ wfl, float* __restrict__ b2w3,
    int* __restrict__ rblk_cnt, int* __restrict__ sblk_cnt, int* __restrict__ blk_cnt) {
  __shared__ int cnt[RNBINS];   // max of {489, 245, 245}
  int b = blockIdx.x, t = threadIdx.x;
  const int* keys; int nkeys, nblk, nb, bl; int* out;
  if (b < RPART_NBLK) {
    keys = rxn_sub; nkeys = E_SUB; nblk = RPART_NBLK; nb = RNBINS; out = rblk_cnt; bl = b;
    if (b < 2) {
      // ---- k_pre: MFMA B-fragments of W23 = W2@W3 (bf16 hi/lo) and b2@W3 ----
      int tid = b * 256 + t;
      if (tid < 512) {
        int lane = tid & 63, jt = (tid >> 6) & 3, ks = tid >> 8;
        int jj = jt * 16 + (lane & 15);
        unsigned short h[8], l[8];
        #pragma unroll
        for (int q = 0; q < 8; ++q) {
          int kk = ks * 32 + (lane >> 4) * 8 + q;
          float w = 0.f;
          #pragma unroll
          for (int m = 0; m < 32; ++m) w = fmaf(W2[kk * 32 + m], W3[m * 64 + jj], w);
          h[q] = bf16_rn(w);
          float hf = __uint_as_float(((unsigned)h[q]) << 16);
          l[q] = bf16_rn(w - hf);
        }
        uint4 H, L;
        H.x = (unsigned)h[0] | ((unsigned)h[1] << 16);
        H.y = (unsigned)h[2] | ((unsigned)h[3] << 16);
        H.z = (unsigned)h[4] | ((unsigned)h[5] << 16);
        H.w = (unsigned)h[6] | ((unsigned)h[7] << 16);
        L.x = (unsigned)l[0] | ((unsigned)l[1] << 16);
        L.y = (unsigned)l[2] | ((unsigned)l[3] << 16);
        L.z = (unsigned)l[4] | ((unsigned)l[5] << 16);
        L.w = (unsigned)l[6] | ((unsigned)l[7] << 16);
        int idx = (ks * 4 + jt) * 64 + lane;
        wfh[idx] = H; wfl[idx] = L;
      }
      if (tid < 64) {
        float s = 0.f;
        #pragma unroll
        for (int m = 0; m < 32; ++m) s = fmaf(b2[m], W3[m * 64 + tid], s);
        b2w3[tid] = s;
      }
    }
  } else if (b < RPART_NBLK + SPART_NBLK) {
    keys = met_sub; nkeys = E_SUB; nblk = SPART_NBLK; nb = NBINS; out = sblk_cnt;
    bl = b - RPART_NBLK;
  } else {
    keys = met_all; nkeys = E_ALL; nblk = PART_NBLK; nb = NBINS; out = blk_cnt;
    bl = b - RPART_NBLK - SPART_NBLK;
    int m = bl * 256 + t;
    if (m < N_MET) conc[m] = __builtin_nontemporal_load(x + m * 8 + 3);
  }
  for (int i = t; i < nb; i += 256) cnt[i] = 0;
  __syncthreads();
  int base = bl * PART_EPB;
  #pragma unroll
  for (int i = 0; i < PART_EPB / 256; ++i) {
    int e = base + i * 256 + t;
    if (e < nkeys) atomicAdd(&cnt[__builtin_nontemporal_load(keys + e) >> 10], 1);
  }
  __syncthreads();
  for (int i = t; i < nb; i += 256) out[i * nblk + bl] = cnt[i];
}

// ==== fused scans ====
static __device__ __forceinline__ void scan1_body(int* ss,
    const int* __restrict__ blk_cnt, int* __restrict__ blk_pref,
    int* __restrict__ bin_tot, int nblk, int j) {
  int t = threadIdx.x;
  int carry = 0;
  for (int c = 0; c < nblk; c += 256) {
    int idx = c + t;
    int v = (idx < nblk) ? blk_cnt[j * nblk + idx] : 0;
    ss[t] = v; __syncthreads();
    for (int d = 1; d < 256; d <<= 1) {
      int a = (t >= d) ? ss[t - d] : 0;
      __syncthreads();
      ss[t] += a;
      __syncthreads();
    }
    if (idx < nblk) blk_pref[j * nblk + idx] = carry + ss[t] - v;
    carry += ss[255];
    __syncthreads();
  }
  if (t == 0) bin_tot[j] = carry;
}

__global__ __launch_bounds__(256) void k_scan1all(
    const int* __restrict__ rblk_cnt, int* __restrict__ rblk_pref, int* __restrict__ rbin_tot,
    const int* __restrict__ sblk_cnt, int* __restrict__ sblk_pref, int* __restrict__ sbin_tot,
    const int* __restrict__ blk_cnt, int* __restrict__ blk_pref, int* __restrict__ bin_tot) {
  __shared__ int ss[256];
  int b = blockIdx.x;
  if (b < RNBINS)
    scan1_body(ss, rblk_cnt, rblk_pref, rbin_tot, RPART_NBLK, b);
  else if (b < RNBINS + NBINS)
    scan1_body(ss, sblk_cnt, sblk_pref, sbin_tot, SPART_NBLK, b - RNBINS);
  else
    scan1_body(ss, blk_cnt, blk_pref, bin_tot, PART_NBLK, b - RNBINS - NBINS);
}

__global__ __launch_bounds__(512) void k_scan2all(
    const int* __restrict__ rbin_tot, int* __restrict__ rbin_start,
    const int* __restrict__ sbin_tot, int* __restrict__ sbin_start,
    const int* __restrict__ bin_tot, int* __restrict__ bin_start) {
  __shared__ int ss[512];
  const int* tot; int* st; int n;
  if (blockIdx.x == 0)      { tot = rbin_tot; st = rbin_start; n = RNBINS; }
  else if (blockIdx.x == 1) { tot = sbin_tot; st = sbin_start; n = NBINS; }
  else                      { tot = bin_tot;  st = bin_start;  n = NBINS; }
  int t = threadIdx.x;
  int v = (t < n) ? tot[t] : 0;
  ss[t] = v; __syncthreads();
  for (int d = 1; d < 512; d <<= 1) {
    int a = (t >= d) ? ss[t - d] : 0;
    __syncthreads();
    ss[t] += a;
    __syncthreads();
  }
  if (t < n) st[t] = ss[t] - v;
}

// ==== block-locally-sorted partition: records leave as contiguous bursts ====
// 512 threads, 8 keys/thread. PACK=true: rec.x carries the full key (bin = rec.x>>10),
// so the binb[] side-array is eliminated (saves 8 KB LDS -> 4 blocks/CU).
template <int NB, bool PACK, typename MakeRec>
static __device__ __forceinline__ void part_sorted(
    const int* __restrict__ keys, int nkeys, int nblk,
    const int* __restrict__ blk_pref, const int* __restrict__ bin_start,
    int2* __restrict__ out, MakeRec make) {
  __shared__ int2 ordered[PART_EPB];                        // 32 KB
  __shared__ unsigned short binb[PACK ? 1 : PART_EPB];      // 8 KB only if !PACK
  __shared__ int cnt[NB];
  __shared__ int gofs[NB];
  __shared__ int ss[PTHREADS];
  int b = blockIdx.x, t = threadIdx.x;
  for (int i = t; i < NB; i += PTHREADS) cnt[i] = 0;
  __syncthreads();
  int base = b * PART_EPB;
  int kbuf[KPB];
  #pragma unroll
  for (int i = 0; i < KPB; ++i) {
    int e = base + i * PTHREADS + t;
    kbuf[i] = (e < nkeys) ? __builtin_nontemporal_load(keys + e) : -1;
    if (kbuf[i] >= 0) atomicAdd(&cnt[kbuf[i] >> 10], 1);
  }
  __syncthreads();
  // single-chunk scan (NB <= PTHREADS); cnt becomes cursor, gofs = global - lstart
  int v = (t < NB) ? cnt[t] : 0;
  ss[t] = v; __syncthreads();
  for (int d = 1; d < PTHREADS; d <<= 1) {
    int a = (t >= d) ? ss[t - d] : 0;
    __syncthreads();
    ss[t] += a;
    __syncthreads();
  }
  int nloc = ss[PTHREADS - 1];
  if (t < NB) {
    int ls = ss[t] - v;
    cnt[t] = ls;  // becomes cursor
    gofs[t] = bin_start[t] + blk_pref[t * nblk + b] - ls;
  }
  __syncthreads();
  // pass B: place records bin-ordered in LDS
  #pragma unroll
  for (int i = 0; i < KPB; ++i) {
    int k = kbuf[i];
    if (k >= 0) {
      int e = base + i * PTHREADS + t;
      int bin = k >> 10;
      int2 rec = make(e, k);
      int pos = atomicAdd(&cnt[bin], 1);  // LDS atomic
      ordered[pos] = rec;
      if (!PACK) binb[pos] = (unsigned short)bin;
    }
  }
  __syncthreads();
  // pass C: ordered, coalesced burst copy
  for (int i = t; i < nloc; i += PTHREADS) {
    int2 rec = ordered[i];
    int bin = PACK ? (int)(((unsigned)rec.x) >> 10) : (int)binb[i];
    out[gofs[bin] + i] = rec;
  }
}

// CSR partition: packed {rloc:10|m:18, sto} by rxn-bin (no spare bits -> binb path)
__global__ __launch_bounds__(PTHREADS) void k_rpart(
    const int* __restrict__ rxn_sub, const int* __restrict__ met_sub,
    const float* __restrict__ sto_sub,
    const int* __restrict__ blk_pref, const int* __restrict__ bin_start,
    int2* __restrict__ bins_rxn) {
  part_sorted<RNBINS, false>(rxn_sub, E_SUB, RPART_NBLK, blk_pref, bin_start, bins_rxn,
    [=] __device__ (int e, int k) {
      int m = __builtin_nontemporal_load(met_sub + e);
      float st = __builtin_nontemporal_load(sto_sub + e);
      int2 rec; rec.x = ((k & (RBINSZ - 1)) << 18) | m; rec.y = __float_as_int(st);
      return rec;
    });
}

// consumption partition: {k(full met idx), sto*v_pre[r]*DT} by met-bin
__global__ __launch_bounds__(PTHREADS) void k_part_sub(
    const int* __restrict__ met_sub, const int* __restrict__ rxn_sub,
    const float* __restrict__ sto_sub, const float* __restrict__ v_pre,
    const int* __restrict__ blk_pref, const int* __restrict__ bin_start,
    int2* __restrict__ bins_sub) {
  part_sorted<NBINS, true>(met_sub, E_SUB, SPART_NBLK, blk_pref, bin_start, bins_sub,
    [=] __device__ (int e, int k) {
      int r = __builtin_nontemporal_load(rxn_sub + e);
      float st = __builtin_nontemporal_load(sto_sub + e);
      float val = st * v_pre[r] * DT;
      int2 rec; rec.x = k; rec.y = __float_as_int(val);
      return rec;
    });
}

// dxdt partition: {k(full met idx), sto*vfin[r]} by met-bin
__global__ __launch_bounds__(PTHREADS) void k_part(
    const int* __restrict__ met_all, const int* __restrict__ rxn_all,
    const float* __restrict__ sto_all, const float* __restrict__ vfin,
    const int* __restrict__ blk_pref, const int* __restrict__ bin_start,
    int2* __restrict__ bins) {
  part_sorted<NBINS, true>(met_all, E_ALL, PART_NBLK, blk_pref, bin_start, bins,
    [=] __device__ (int e, int k) {
      int r = __builtin_nontemporal_load(rxn_all + e);
      float st = __builtin_nontemporal_load(sto_all + e);
      float val = st * vfin[r];
      int2 rec; rec.x = k; rec.y = __float_as_int(val);
      return rec;
    });
}

// ==== CSR per-bin local sort -> edges8 CSR order + off[] ====
// 512 threads, NO LDS staging: each block's bins_rxn slice (~8 KB) was just
// written/streamed, so the pass-2 re-read is an L2 hit.
__global__ __launch_bounds__(512) void k_rbin(
    const int2* __restrict__ bins_rxn, const int* __restrict__ rbin_start,
    const int* __restrict__ rbin_tot, int2* __restrict__ edges8, int* __restrict__ off) {
  __shared__ int lcnt[RBINSZ];
  __shared__ int lcur[RBINSZ];
  __shared__ int ss[512];
  int j = blockIdx.x, t = threadIdx.x;
  int base = rbin_start[j], n = rbin_tot[j];
  for (int i = t; i < RBINSZ; i += 512) lcnt[i] = 0;
  __syncthreads();
  for (int i = t; i < n; i += 512) {
    int2 rec = bins_rxn[base + i];
    atomicAdd(&lcnt[((unsigned)rec.x) >> 18], 1);
  }
  __syncthreads();
  int s0 = lcnt[2 * t], s1 = lcnt[2 * t + 1];
  int tsum = s0 + s1;
  ss[t] = tsum; __syncthreads();
  for (int d = 1; d < 512; d <<= 1) {
    int a = (t >= d) ? ss[t - d] : 0;
    __syncthreads();
    ss[t] += a;
    __syncthreads();
  }
  int run = ss[t] - tsum;
  lcur[2 * t] = run;
  lcur[2 * t + 1] = run + s0;
  __syncthreads();
  int R0 = j * RBINSZ;
  for (int rl = t; rl < RBINSZ; rl += 512) {
    int r = R0 + rl;
    if (r < N_RXN) off[r] = base + lcur[rl];
  }
  if (j == 0 && t == 0) off[N_RXN] = E_SUB;
  __syncthreads();
  for (int i = t; i < n; i += 512) {
    int2 rec = bins_rxn[base + i];
    int pos = atomicAdd(&lcur[((unsigned)rec.x) >> 18], 1);
    int2 o; o.x = rec.x & 0x3FFFF; o.y = rec.y;
    edges8[base + pos] = o;
  }
}

// ---- k_edge_mv: fused edge tanh-sum + MFMA (T never leaves the CU) ----
// Math: sum_e tanh(x_e) = n - 2 * sum_e 1/(1 + exp2(C2*x_e)), C2 = 2*log2(e),
// with C2 folded into the per-lane W1/b1 constants.
// 1-deep software pipeline: the ds_reads for pair k+1 issue BEFORE the compute
// of pair k, hiding ~120cy LDS latency under ~40cy of VALU/trans work.
// Accumulation order is identical to the non-pipelined version (S0=even, S1=odd).
static __device__ __forceinline__ float edge_rsum_lds(int o0, int o1, int estart,
                                                      const float2* ep,
                                                      float w1x, float w1y, float b1j) {
  float S0 = 0.f, S1 = 0.f;
  int c = o0 - estart;
  int cend = o1 - estart;
  if (c + 1 < cend) {
    float2 e0 = ep[c], e1 = ep[c + 1];
    c += 2;
    while (c + 1 < cend) {
      float2 n0 = ep[c], n1 = ep[c + 1];   // prefetch next pair (uniform branch-free)
      S0 += RCPF(EXP2F(fmaf(e0.x, w1x, fmaf(e0.y, w1y, b1j))) + 1.0f);
      S1 += RCPF(EXP2F(fmaf(e1.x, w1x, fmaf(e1.y, w1y, b1j))) + 1.0f);
      e0 = n0; e1 = n1;
      c += 2;
    }
    S0 += RCPF(EXP2F(fmaf(e0.x, w1x, fmaf(e0.y, w1y, b1j))) + 1.0f);
    S1 += RCPF(EXP2F(fmaf(e1.x, w1x, fmaf(e1.y, w1y, b1j))) + 1.0f);
  }
  if (c < cend) {
    float2 e0 = ep[c];
    S0 += RCPF(EXP2F(fmaf(e0.x, w1x, fmaf(e0.y, w1y, b1j))) + 1.0f);
  }
  return S0 + S1;
}

static __device__ __forceinline__ float edge_rsum_glob(int o0, int o1,
                                                       const int2* edges8,
                                                       const float* conc,
                                                       float w1x, float w1y, float b1j) {
  float S = 0.f;
  for (int c = o0; c < o1; ++c) {
    int2 rec = edges8[c];
    float cc = conc[rec.x];
    float t0 = fmaf(cc, w1x, fmaf(__int_as_float(rec.y), w1y, b1j));
    S += RCPF(EXP2F(t0) + 1.0f);
  }
  return S;
}

__global__ __launch_bounds__(THREADS) void k_edge_mv(
    const int* __restrict__ off, const int2* __restrict__ edges8,
    const float* __restrict__ conc,
    const float* __restrict__ W1, const float* __restrict__ b1,
    const uint4* __restrict__ wfh, const uint4* __restrict__ wfl,
    const float* __restrict__ b2w3, const float* __restrict__ b3,
    const float* __restrict__ W4, const float* __restrict__ b4,
    const float* __restrict__ log_k, float* __restrict__ v_pre) {
  __shared__ int off_s[RXN_PER_BLK + 1];
  __shared__ float2 se[EDGE_CAP];
  __shared__ __align__(16) unsigned short thi[4][16][TPAD];  // 9.2 KB
  __shared__ __align__(16) unsigned short tlo[4][16][TPAD];  // 9.2 KB

  int tid = threadIdx.x;
  int lane = tid & 63;
  int wv = tid >> 6;
  int R0 = blockIdx.x * RXN_PER_BLK;

  for (int i = tid; i <= RXN_PER_BLK; i += THREADS) {
    int r = R0 + i;
    off_s[i] = off[r > N_RXN ? N_RXN : r];
  }
  __syncthreads();
  int estart = off_s[0];
  int nE = off_s[RXN_PER_BLK] - estart;
  bool fits = (nE <= EDGE_CAP);
  if (fits) {
    for (int i = tid; i < nE; i += THREADS) {
      int2 rec = edges8[estart + i];
      se[i] = make_float2(conc[rec.x], __int_as_float(rec.y));
    }
  }

  const float C2 = 2.8853900817779268f;  // 2*log2(e)
  float w1x = W1[lane] * C2, w1y = W1[64 + lane] * C2, b1j = b1[lane] * C2;

  int rbase = R0 + wv * 64;
  int o0l = off_s[wv * 64 + lane];
  int o1l = off_s[wv * 64 + lane + 1];

  int col = lane & 15, rowg = lane >> 4;

  // per-lane epilogue constants (tiny, L1/L2 hits)
  float w4c[4], bwc[4], b3c[4];
  #pragma unroll
  for (int jt = 0; jt < 4; ++jt) {
    int jj = jt * 16 + col;
    w4c[jt] = W4[jj]; bwc[jt] = b2w3[jj]; b3c[jt] = b3[jj];
  }
  float b40 = b4[0];

  __syncthreads();

  // opaque per-tile pointers: keep B-fragment loads inside the tile loop
  const uint4* wfh_v = wfh;
  const uint4* wfl_v = wfl;

  unsigned short* thw = &thi[wv][0][0];
  unsigned short* tlw = &tlo[wv][0][0];

  int o0 = bcast_i(o0l, 0);   // o0 of reaction i is o1 of reaction i-1: carry it
  #pragma clang loop unroll(disable)
  for (int tt = 0; tt < 4; ++tt) {
    asm volatile("" : "+v"(wfh_v), "+v"(wfl_v));
    int rt = rbase + tt * 16;
    // ---- edge phase for 16 reactions (lane = feature) ----
    #pragma clang loop unroll(disable)
    for (int i = 0; i < 16; ++i) {
      int li = tt * 16 + i;
      int o1 = bcast_i(o1l, li);
      float S = fits ? edge_rsum_lds(o0, o1, estart, se, w1x, w1y, b1j)
                     : edge_rsum_glob(o0, o1, edges8, conc, w1x, w1y, b1j);
      float T = (float)(o1 - o0) - 2.0f * S;   // out-of-range rxns: o0==o1 -> T=0
      unsigned short hi = bf16_rn(T);
      float hf = __uint_as_float(((unsigned)hi) << 16);
      thw[i * TPAD + lane] = hi;
      tlw[i * TPAD + lane] = bf16_rn(T - hf);
      o0 = o1;
    }
    // ---- MFMA phase: wave-local LDS RAW (compiler inserts lgkmcnt) ----
    bf16x8 ah[2], al[2];
    {
      int fo = col * TPAD + rowg * 8;       // u16 elements; TPAD=72 -> 9 uint4/row
      const uint4* ph = (const uint4*)thw;
      const uint4* pl = (const uint4*)tlw;
      ah[0] = __builtin_bit_cast(bf16x8, ph[fo >> 3]);
      ah[1] = __builtin_bit_cast(bf16x8, ph[(fo + 32) >> 3]);
      al[0] = __builtin_bit_cast(bf16x8, pl[fo >> 3]);
      al[1] = __builtin_bit_cast(bf16x8, pl[(fo + 32) >> 3]);
    }
    f32x4 acc[4];
    #pragma unroll
    for (int jt = 0; jt < 4; ++jt) acc[jt] = (f32x4){0.f, 0.f, 0.f, 0.f};
    #pragma unroll
    for (int jt = 0; jt < 4; ++jt) {
      #pragma unroll
      for (int ks = 0; ks < 2; ++ks) {
        int bidx = (ks * 4 + jt) * 64 + lane;
        bf16x8 bh = __builtin_bit_cast(bf16x8, wfh_v[bidx]);
        bf16x8 bl = __builtin_bit_cast(bf16x8, wfl_v[bidx]);
        acc[jt] = __builtin_amdgcn_mfma_f32_16x16x32_bf16(ah[ks], bh, acc[jt], 0, 0, 0);
        acc[jt] = __builtin_amdgcn_mfma_f32_16x16x32_bf16(ah[ks], bl, acc[jt], 0, 0, 0);
        acc[jt] = __builtin_amdgcn_mfma_f32_16x16x32_bf16(al[ks], bh, acc[jt], 0, 0, 0);
      }
    }
    // ---- epilogue for reactions rt .. rt+15 ----
    float nq[4];
    #pragma unroll
    for (int q = 0; q < 4; ++q) {
      int idx = tt * 16 + rowg * 4 + q + wv * 64;
      nq[q] = (float)(off_s[idx + 1] - off_s[idx]);
    }
    #pragma unroll
    for (int q = 0; q < 4; ++q) {
      float s = 0.f;
      #pragma unroll
      for (int jt = 0; jt < 4; ++jt) {
        float u = acc[jt][q] + nq[q] * bwc[jt] + b3c[jt];
        s += fast_tanh(u) * w4c[jt];
      }
      s += __shfl_xor(s, 1, 64);
      s += __shfl_xor(s, 2, 64);
      s += __shfl_xor(s, 4, 64);
      s += __shfl_xor(s, 8, 64);
      if (col == 0) {
        int r = rt + rowg * 4 + q;
        float lk = (r < N_RXN) ? log_k[r] : 0.f;
        float racc = s + b40;
        float k10 = __expf(lk * 2.3025850929940457f);
        float sp = (racc > 15.f) ? racc : __logf(1.f + __expf(racc));
        if (r < N_RXN) v_pre[r] = k10 * sp;
      }
    }
  }
}

// accumulate consumption totals per bin + fused met_scale
__global__ __launch_bounds__(512) void k_bins_sub(
    const int2* __restrict__ bins_sub, const int* __restrict__ bin_start,
    const int* __restrict__ bin_tot, const float* __restrict__ conc,
    float* __restrict__ met_scale) {
  __shared__ float acc[BINSZ];
  int j = blockIdx.x, t = threadIdx.x;
  for (int i = t; i < BINSZ; i += 512) acc[i] = 0.f;
  __syncthreads();
  int s0 = bin_start[j], n = bin_tot[j];
  for (int i = t; i < n; i += 512) {
    int2 rec = bins_sub[s0 + i];
    atomicAdd(&acc[rec.x & (BINSZ - 1)], __int_as_float(rec.y));  // LDS fp32 atomic
  }
  __syncthreads();
  int m0 = j * BINSZ;
  for (int i = t; i < BINSZ; i += 512) {
    int m = m0 + i;
    if (m < N_MET) {
      float tot = acc[i];
      met_scale[m] = (tot > 1e-12f) ? fminf(conc[m] / tot, 1.0f) : 1.0f;
    }
  }
}

// ---- k_rscale: per-rxn min over CSR slice (4 lanes/rxn), fused vfin write ----
__global__ __launch_bounds__(256) void k_rscale(
    const int* __restrict__ off, const int2* __restrict__ edges8,
    const float* __restrict__ met_scale, const float* __restrict__ v_pre,
    float* __restrict__ vfin) {
  __shared__ int soff[MV_RPB + 1];
  int tid = threadIdx.x, lane = tid & 63, w = tid >> 6;
  int B0 = blockIdx.x * MV_RPB;
  for (int i = tid; i <= MV_RPB; i += 256) {
    int r = B0 + i;
    soff[i] = off[r > N_RXN ? N_RXN : r];
  }
  __syncthreads();

  int rloc = w * 16 + (lane >> 2);
  int o0 = soff[rloc], o1 = soff[rloc + 1];
  float sc = 1.0f;
  for (int c = o0 + (lane & 3); c < o1; c += 4) {
    sc = fminf(sc, met_scale[edges8[c].x]);
  }
  sc = fminf(sc, __shfl_xor(sc, 1, 64));
  sc = fminf(sc, __shfl_xor(sc, 2, 64));
  if ((lane & 3) == 0) {
    int r = B0 + rloc;
    if (r < N_RXN) vfin[r] = v_pre[r] * sc;
  }
}

__global__ __launch_bounds__(512) void k_bins(const int2* __restrict__ bins,
                                              const int* __restrict__ bin_start,
                                              const int* __restrict__ bin_tot,
                                              float* __restrict__ dxdt) {
  __shared__ float acc[BINSZ];
  int j = blockIdx.x, t = threadIdx.x;
  for (int i = t; i < BINSZ; i += 512) acc[i] = 0.f;
  __syncthreads();
  int s0 = bin_start[j], n = bin_tot[j];
  for (int i = t; i < n; i += 512) {
    int2 rec = bins[s0 + i];
    atomicAdd(&acc[rec.x & (BINSZ - 1)], __int_as_float(rec.y));  // LDS fp32 atomic
  }
  __syncthreads();
  int m0 = j * BINSZ;
  for (int i = t; i < BINSZ; i += 512) {
    int m = m0 + i;
    if (m < N_MET) dxdt[m] = acc[i];
  }
}

extern "C" void kernel_launch(void* const* d_in, const int* in_sizes, int n_in,
                              void* d_out, int out_size, void* d_ws, size_t ws_size,
                              hipStream_t stream) {
  const float* x       = (const float*)d_in[0];
  const int*   met_sub = (const int*)d_in[1];
  const int*   rxn_sub = (const int*)d_in[2];
  const float* sto_sub = (const float*)d_in[3];
  const int*   met_all = (const int*)d_in[4];
  const int*   rxn_all = (const int*)d_in[5];
  const float* sto_all = (const float*)d_in[6];
  const float* W1    = (const float*)d_in[7];
  const float* b1    = (const float*)d_in[8];
  const float* W2    = (const float*)d_in[9];
  const float* b2    = (const float*)d_in[10];
  const float* W3    = (const float*)d_in[11];
  const float* b3    = (const float*)d_in[12];
  const float* W4    = (const float*)d_in[13];
  const float* b4    = (const float*)d_in[14];
  const float* log_k = (const float*)d_in[15];
  float* dxdt = (float*)d_out;

  char* ws = (char*)d_ws;
  size_t p = 0;
  auto alloc = [&](size_t bytes) -> void* {
    void* r = (void*)(ws + p);
    p += (bytes + 255) & ~(size_t)255;
    return r;
  };
  int*    off        = (int*)alloc(sizeof(int) * (N_RXN + 1));
  uint4*  wfh        = (uint4*)alloc(sizeof(uint4) * 512);
  uint4*  wfl        = (uint4*)alloc(sizeof(uint4) * 512);
  float*  b2w3       = (float*)alloc(sizeof(float) * 64);
  float*  v_pre      = (float*)alloc(sizeof(float) * N_RXN);
  float*  vfin       = (float*)alloc(sizeof(float) * N_RXN);
  float*  conc       = (float*)alloc(sizeof(float) * N_MET);
  float*  met_scale  = (float*)alloc(sizeof(float) * N_MET);
  int2*   edges8     = (int2*)alloc(sizeof(int2) * E_SUB);      // CSR {m, sto}
  int2*   bins_rxn   = (int2*)alloc(sizeof(int2) * E_SUB);      // rxn-binned staging
  int2*   bins_sub   = (int2*)alloc(sizeof(int2) * E_SUB);      // met-binned {k, val}
  int2*   bins       = (int2*)alloc(sizeof(int2) * E_ALL);      // met-binned {k, val}
  int*    rblk_cnt   = (int*)alloc(sizeof(int) * RNBINS * RPART_NBLK);
  int*    rblk_pref  = (int*)alloc(sizeof(int) * RNBINS * RPART_NBLK);
  int*    sblk_cnt   = (int*)alloc(sizeof(int) * NBINS * SPART_NBLK);
  int*    sblk_pref  = (int*)alloc(sizeof(int) * NBINS * SPART_NBLK);
  int*    blk_cnt    = (int*)alloc(sizeof(int) * NBINS * PART_NBLK);
  int*    blk_pref   = (int*)alloc(sizeof(int) * NBINS * PART_NBLK);
  int*    rbin_tot   = (int*)alloc(sizeof(int) * 512);
  int*    rbin_start = (int*)alloc(sizeof(int) * 512);
  int*    sbin_tot   = (int*)alloc(sizeof(int) * 512);
  int*    sbin_start = (int*)alloc(sizeof(int) * 512);
  int*    bin_tot    = (int*)alloc(sizeof(int) * 512);
  int*    bin_start  = (int*)alloc(sizeof(int) * 512);
  (void)in_sizes; (void)n_in; (void)out_size; (void)ws_size;

  // no global memsets needed: every buffer is fully written before it is read

  // fused: all 3 bin-count histograms + conc extraction + W23/b2w3 precompute
  k_bc3<<<RPART_NBLK + SPART_NBLK + PART_NBLK, 256, 0, stream>>>(
      rxn_sub, met_sub, met_all, x, conc, W2, W3, b2, wfh, wfl, b2w3,
      rblk_cnt, sblk_cnt, blk_cnt);
  // fused scans
  k_scan1all<<<RNBINS + NBINS + NBINS, 256, 0, stream>>>(
      rblk_cnt, rblk_pref, rbin_tot, sblk_cnt, sblk_pref, sbin_tot,
      blk_cnt, blk_pref, bin_tot);
  k_scan2all<<<3, 512, 0, stream>>>(rbin_tot, rbin_start, sbin_tot, sbin_start,
                                    bin_tot, bin_start);

  // CSR build (counting sort, no global atomics)
  k_rpart<<<RPART_NBLK, PTHREADS, 0, stream>>>(rxn_sub, met_sub, sto_sub,
                                               rblk_pref, rbin_start, bins_rxn);
  k_rbin<<<RNBINS, 512, 0, stream>>>(bins_rxn, rbin_start, rbin_tot, edges8, off);

  // fused MLP: edge tanh-sum + MFMA + epilogue -> v_pre (T stays on-CU)
  k_edge_mv<<<(N_RXN + RXN_PER_BLK - 1) / RXN_PER_BLK, THREADS, 0, stream>>>(
      off, edges8, conc, W1, b1, wfh, wfl, b2w3, b3, W4, b4, log_k, v_pre);

  // consumption totals -> met_scale (binned, fused scale)
  k_part_sub<<<SPART_NBLK, PTHREADS, 0, stream>>>(met_sub, rxn_sub, sto_sub, v_pre,
                                                  sblk_pref, sbin_start, bins_sub);
  k_bins_sub<<<NBINS, 512, 0, stream>>>(bins_sub, sbin_start, sbin_tot, conc, met_scale);

  // rxn scale + final v
  k_rscale<<<(N_RXN + MV_RPB - 1) / MV_RPB, 256, 0, stream>>>(
      off, edges8, met_scale, v_pre, vfin);

  // dxdt (binned)
  k_part<<<PART_NBLK, PTHREADS, 0, stream>>>(met_all, rxn_all, sto_all, vfin,
                                             blk_pref, bin_start, bins);
  k_bins<<<NBINS, 512, 0, stream>>>(bins, bin_start, bin_tot, dxdt);
}